// Round 1
// baseline (62461.108 us; speedup 1.0000x reference)
//
#include <hip/hip_runtime.h>
#include <hip/hip_bf16.h>
#include <math.h>

// ---- Model constants ----
#define BB 16
#define CC 3
#define IMG 512
#define PP 16
#define HH 384
#define NHEAD 6
#define DH 64
#define LL 12
#define II 1536
#define NC 1000
#define NPATCH 1024
#define SS 1025
#define MROWS (BB * SS)   // 16400

// ======================= Patch embedding =======================
// grid: (S=1025, B); block: 384 threads (one per output channel)
__global__ __launch_bounds__(384) void patch_embed_kernel(
    const float* __restrict__ x, const float* __restrict__ cw,
    const float* __restrict__ cb, const float* __restrict__ cls,
    const float* __restrict__ pos, float* __restrict__ h)
{
    int r = blockIdx.x;     // row in sequence: 0 = cls, 1..1024 = patches
    int b = blockIdx.y;
    int o = threadIdx.x;    // output channel 0..383

    if (r == 0) {
        h[((size_t)b * SS) * HH + o] = cls[o] + pos[o];
        return;
    }

    __shared__ float patch[CC * PP * PP];   // 768 floats
    int p = r - 1;
    int pi = p >> 5;   // patch row (0..31)
    int pj = p & 31;   // patch col

    for (int idx = threadIdx.x; idx < CC * PP * PP; idx += 384) {
        int c  = idx >> 8;          // /256
        int rem = idx & 255;
        int py = rem >> 4;
        int px = rem & 15;
        patch[idx] = x[(((size_t)b * CC + c) * IMG + (pi * PP + py)) * IMG
                       + (pj * PP + px)];
    }
    __syncthreads();

    float acc = cb[o];
    const float* wrow = cw + (size_t)o * (CC * PP * PP);
    #pragma unroll 4
    for (int kk = 0; kk < CC * PP * PP; ++kk)
        acc += patch[kk] * wrow[kk];

    h[((size_t)b * SS + r) * HH + o] = acc + pos[(size_t)r * HH + o];
}

// ======================= LayerNorm =======================
// one wave (64 lanes) per row; block = 256 → 4 rows/block
__global__ __launch_bounds__(256) void ln_kernel(
    const float* __restrict__ x, const float* __restrict__ w,
    const float* __restrict__ b, float* __restrict__ out, int nrows)
{
    int wave = threadIdx.x >> 6;
    int lane = threadIdx.x & 63;
    int row = blockIdx.x * 4 + wave;
    if (row >= nrows) return;

    const float* xr = x + (size_t)row * HH;
    float vals[6];
    float s = 0.f;
    #pragma unroll
    for (int i = 0; i < 6; ++i) { vals[i] = xr[lane + 64 * i]; s += vals[i]; }
    #pragma unroll
    for (int mask = 32; mask >= 1; mask >>= 1) s += __shfl_xor(s, mask);
    float mean = s * (1.f / HH);
    float vs = 0.f;
    #pragma unroll
    for (int i = 0; i < 6; ++i) { float d = vals[i] - mean; vs += d * d; }
    #pragma unroll
    for (int mask = 32; mask >= 1; mask >>= 1) vs += __shfl_xor(vs, mask);
    float rstd = rsqrtf(vs * (1.f / HH) + 1e-5f);

    float* outr = out + (size_t)row * HH;
    #pragma unroll
    for (int i = 0; i < 6; ++i) {
        int jj = lane + 64 * i;
        outr[jj] = (vals[i] - mean) * rstd * w[jj] + b[jj];
    }
}

// ======================= Tiled fp32 GEMM =======================
// C[M,N] = epilogue(A[M,K] @ W[K,N] + bias[N]) (+ res[M,N])
#define BM 64
#define BN 64
#define BK 16

template<bool DOGELU, bool DORES>
__global__ __launch_bounds__(256) void gemm_kernel(
    const float* __restrict__ A, const float* __restrict__ W,
    const float* __restrict__ bias, const float* __restrict__ res,
    float* __restrict__ C, int M, int N, int K)
{
    __shared__ float As[BK][BM + 4];   // As[k][m], stride 68 floats (16B-aligned rows)
    __shared__ float Bs[BK][BN + 4];

    int t  = threadIdx.x;
    int bm = blockIdx.x * BM;
    int bn = blockIdx.y * BN;
    int tx = t & 15;    // n-direction
    int ty = t >> 4;    // m-direction

    float acc[4][4] = {};

    for (int k0 = 0; k0 < K; k0 += BK) {
        {
            int idx = t;
            #pragma unroll
            for (int i = 0; i < 4; ++i, idx += 256) {
                int kk = idx & 15, mm = idx >> 4;
                int m = bm + mm;
                As[kk][mm] = (m < M) ? A[(size_t)m * K + k0 + kk] : 0.f;
            }
        }
        {
            int idx = t;
            #pragma unroll
            for (int i = 0; i < 4; ++i, idx += 256) {
                int nn = idx & 63, kk = idx >> 6;
                Bs[kk][nn] = W[(size_t)(k0 + kk) * N + bn + nn];
            }
        }
        __syncthreads();

        #pragma unroll
        for (int k = 0; k < BK; ++k) {
            float4 a4 = *(const float4*)&As[k][ty * 4];
            float4 b4 = *(const float4*)&Bs[k][tx * 4];
            float a[4] = {a4.x, a4.y, a4.z, a4.w};
            float bfrag[4] = {b4.x, b4.y, b4.z, b4.w};
            #pragma unroll
            for (int i = 0; i < 4; ++i)
                #pragma unroll
                for (int j = 0; j < 4; ++j)
                    acc[i][j] += a[i] * bfrag[j];
        }
        __syncthreads();
    }

    #pragma unroll
    for (int i = 0; i < 4; ++i) {
        int m = bm + ty * 4 + i;
        if (m >= M) continue;
        #pragma unroll
        for (int j = 0; j < 4; ++j) {
            int n = bn + tx * 4 + j;
            float c = acc[i][j] + bias[n];
            if (DOGELU) {
                float u = c;
                c = 0.5f * u * (1.f + tanhf(0.7978845608028654f *
                                            (u + 0.044715f * u * u * u)));
            }
            if (DORES) c += res[(size_t)m * N + n];
            C[(size_t)m * N + n] = c;
        }
    }
}

// ======================= Attention =======================
// grid: (ceil(S/QT)=129, NH, B); block 256
#define QT 8
#define SCS 1044   // score-row stride (conflict-free for 8-row parallel softmax)

__global__ __launch_bounds__(256) void attn_kernel(
    const float* __restrict__ q, const float* __restrict__ k,
    const float* __restrict__ v, float* __restrict__ o)
{
    __shared__ float qs[QT][65];
    __shared__ float ks[64][65];
    __shared__ float sc[QT][SCS];

    int t    = threadIdx.x;
    int q0   = blockIdx.x * QT;
    int head = blockIdx.y;
    int b    = blockIdx.z;
    size_t base = ((size_t)b * SS) * HH + head * DH;

    // load Q tile
    for (int idx = t; idx < QT * DH; idx += 256) {
        int r = idx >> 6, d = idx & 63;
        int qi = q0 + r;
        qs[r][d] = (qi < SS) ? q[base + (size_t)qi * HH + d] : 0.f;
    }
    __syncthreads();

    // scores (K staged in LDS chunks of 64)
    for (int c0 = 0; c0 < SS; c0 += 64) {
        int csz = SS - c0; if (csz > 64) csz = 64;
        __syncthreads();
        for (int idx = t; idx < 64 * 64; idx += 256) {
            int j = idx >> 6, d = idx & 63;
            ks[j][d] = (j < csz) ? k[base + (size_t)(c0 + j) * HH + d] : 0.f;
        }
        __syncthreads();
        #pragma unroll
        for (int pi2 = 0; pi2 < 2; ++pi2) {
            int pi = t + 256 * pi2;
            int r = pi & 7, jj = pi >> 3;
            if (jj < csz) {
                float s = 0.f;
                #pragma unroll
                for (int d = 0; d < DH; ++d) s += qs[r][d] * ks[jj][d];
                sc[r][c0 + jj] = s * 0.125f;   // 1/sqrt(64)
            }
        }
    }
    __syncthreads();

    // softmax: 8 rows x 32 lanes
    {
        int r = t >> 5, lane = t & 31;
        float m = -1e30f;
        for (int j = lane; j < SS; j += 32) m = fmaxf(m, sc[r][j]);
        #pragma unroll
        for (int mask = 16; mask >= 1; mask >>= 1) m = fmaxf(m, __shfl_xor(m, mask));
        float ssum = 0.f;
        for (int j = lane; j < SS; j += 32) {
            float e = __expf(sc[r][j] - m);
            sc[r][j] = e;
            ssum += e;
        }
        #pragma unroll
        for (int mask = 16; mask >= 1; mask >>= 1) ssum += __shfl_xor(ssum, mask);
        float inv = 1.f / ssum;
        for (int j = lane; j < SS; j += 32) sc[r][j] *= inv;
    }
    __syncthreads();

    // PV: 4 wave-slots x 64 d; each thread covers 2 query rows
    {
        int d = t & 63, slot = t >> 6;
        int r0 = slot, r1 = slot + 4;
        float acc0 = 0.f, acc1 = 0.f;
        #pragma unroll 4
        for (int j = 0; j < SS; ++j) {
            float vv = v[base + (size_t)j * HH + d];
            acc0 += sc[r0][j] * vv;
            acc1 += sc[r1][j] * vv;
        }
        int qi0 = q0 + r0, qi1 = q0 + r1;
        if (qi0 < SS) o[base + (size_t)qi0 * HH + d] = acc0;
        if (qi1 < SS) o[base + (size_t)qi1 * HH + d] = acc1;
    }
}

// ======================= Classifier =======================
__global__ __launch_bounds__(256) void cls_kernel(
    const float* __restrict__ h, const float* __restrict__ wc,
    const float* __restrict__ bc, float* __restrict__ out)
{
    __shared__ float hr[HH];
    int b = blockIdx.x, t = threadIdx.x;
    for (int i = t; i < HH; i += 256) hr[i] = h[(size_t)b * SS * HH + i];
    __syncthreads();
    for (int n = t; n < NC; n += 256) {
        float acc = bc[n];
        #pragma unroll 4
        for (int kk = 0; kk < HH; ++kk) acc += hr[kk] * wc[(size_t)kk * NC + n];
        out[b * NC + n] = acc;
    }
}

// ======================= Launch =======================
extern "C" void kernel_launch(void* const* d_in, const int* in_sizes, int n_in,
                              void* d_out, int out_size, void* d_ws, size_t ws_size,
                              hipStream_t stream) {
    const float* x        = (const float*)d_in[0];
    const float* conv_w   = (const float*)d_in[1];
    const float* conv_b   = (const float*)d_in[2];
    const float* cls_tok  = (const float*)d_in[3];
    const float* pos_emb  = (const float*)d_in[4];
    const float* ln1_w    = (const float*)d_in[5];
    const float* ln1_b    = (const float*)d_in[6];
    const float* wq       = (const float*)d_in[7];
    const float* bq       = (const float*)d_in[8];
    const float* wk       = (const float*)d_in[9];
    const float* bk       = (const float*)d_in[10];
    const float* wv       = (const float*)d_in[11];
    const float* bv       = (const float*)d_in[12];
    const float* wo       = (const float*)d_in[13];
    const float* bo       = (const float*)d_in[14];
    const float* ln2_w    = (const float*)d_in[15];
    const float* ln2_b    = (const float*)d_in[16];
    const float* w1       = (const float*)d_in[17];
    const float* b1       = (const float*)d_in[18];
    const float* w2       = (const float*)d_in[19];
    const float* b2       = (const float*)d_in[20];
    const float* wc       = (const float*)d_in[21];
    const float* bc       = (const float*)d_in[22];
    float* out = (float*)d_out;

    const size_t BSH = (size_t)BB * SS * HH;   // 6,297,600 floats
    float* ws = (float*)d_ws;
    float* h  = ws;
    float* hn = ws + BSH;
    float* qb = ws + 2 * BSH;
    float* kb = ws + 3 * BSH;
    float* vb = ws + 4 * BSH;
    float* tb = ws + 5 * BSH;
    float* mb = qb;   // MLP intermediate aliases q..t (B*S*I == 4*B*S*H)

    patch_embed_kernel<<<dim3(SS, BB), 384, 0, stream>>>(
        x, conv_w, conv_b, cls_tok, pos_emb, h);

    const int M = MROWS;
    dim3 gH(257, HH / BN);    // N=384
    dim3 gI(257, II / BN);    // N=1536

    for (int l = 0; l < LL; ++l) {
        const float* l1w = ln1_w + (size_t)l * HH;
        const float* l1b = ln1_b + (size_t)l * HH;
        const float* l2w = ln2_w + (size_t)l * HH;
        const float* l2b = ln2_b + (size_t)l * HH;
        const float* wq_l = wq + (size_t)l * HH * HH;
        const float* wk_l = wk + (size_t)l * HH * HH;
        const float* wv_l = wv + (size_t)l * HH * HH;
        const float* wo_l = wo + (size_t)l * HH * HH;
        const float* bq_l = bq + (size_t)l * HH;
        const float* bk_l = bk + (size_t)l * HH;
        const float* bv_l = bv + (size_t)l * HH;
        const float* bo_l = bo + (size_t)l * HH;
        const float* w1_l = w1 + (size_t)l * HH * II;
        const float* b1_l = b1 + (size_t)l * II;
        const float* w2_l = w2 + (size_t)l * II * HH;
        const float* b2_l = b2 + (size_t)l * HH;

        ln_kernel<<<4100, 256, 0, stream>>>(h, l1w, l1b, hn, M);

        gemm_kernel<false, false><<<gH, 256, 0, stream>>>(hn, wq_l, bq_l, nullptr, qb, M, HH, HH);
        gemm_kernel<false, false><<<gH, 256, 0, stream>>>(hn, wk_l, bk_l, nullptr, kb, M, HH, HH);
        gemm_kernel<false, false><<<gH, 256, 0, stream>>>(hn, wv_l, bv_l, nullptr, vb, M, HH, HH);

        attn_kernel<<<dim3(129, NHEAD, BB), 256, 0, stream>>>(qb, kb, vb, tb);

        gemm_kernel<false, true><<<gH, 256, 0, stream>>>(tb, wo_l, bo_l, h, h, M, HH, HH);

        ln_kernel<<<4100, 256, 0, stream>>>(h, l2w, l2b, hn, M);

        gemm_kernel<true, false><<<gI, 256, 0, stream>>>(hn, w1_l, b1_l, nullptr, mb, M, II, HH);
        gemm_kernel<false, true><<<gH, 256, 0, stream>>>(mb, w2_l, b2_l, h, h, M, HH, II);
    }

    cls_kernel<<<BB, 256, 0, stream>>>(h, wc, bc, out);
}

// Round 2
// 5404.877 us; speedup vs baseline: 11.5564x; 11.5564x over previous
//
#include <hip/hip_runtime.h>
#include <hip/hip_bf16.h>
#include <math.h>

// ---- Model constants ----
#define BB 16
#define HH 384
#define NHEAD 6
#define DH 64
#define LL 12
#define II 1536
#define NC 1000
#define SS 1025
#define MROWS (BB * SS)      // 16400
#define KPATCH 768           // 3*16*16
#define MPATCH (BB * 1024)   // 16384

typedef __hip_bfloat16 bf16;
typedef __attribute__((ext_vector_type(8))) short bh8;   // 8 bf16 = 4 VGPRs (MFMA A/B frag)
typedef __attribute__((ext_vector_type(4))) float f4x;   // MFMA C/D frag

// ======================= transpose + cast: [L][K][N] f32 -> [L][N][K] bf16 =======================
__global__ __launch_bounds__(256) void transpose_cast_kernel(
    const float* __restrict__ in, bf16* __restrict__ out, int K, int N)
{
    __shared__ float tile[32][33];
    int l = blockIdx.z;
    const float* ip = in + (size_t)l * K * N;
    bf16* op = out + (size_t)l * N * K;
    int n0 = blockIdx.x * 32, k0 = blockIdx.y * 32;
    int tx = threadIdx.x & 31, ty = threadIdx.x >> 5;   // 32 x 8
    #pragma unroll
    for (int i = 0; i < 32; i += 8)
        tile[ty + i][tx] = ip[(size_t)(k0 + ty + i) * N + n0 + tx];
    __syncthreads();
    #pragma unroll
    for (int i = 0; i < 32; i += 8)
        op[(size_t)(n0 + ty + i) * K + k0 + tx] = __float2bfloat16(tile[tx][ty + i]);
}

// ======================= plain cast f32 -> bf16 =======================
__global__ __launch_bounds__(256) void cast_kernel(
    const float* __restrict__ in, bf16* __restrict__ out, int n)
{
    int i = blockIdx.x * 1024 + threadIdx.x * 4;
    if (i + 3 < n) {
        float4 v = *(const float4*)&in[i];
        out[i]   = __float2bfloat16(v.x);
        out[i+1] = __float2bfloat16(v.y);
        out[i+2] = __float2bfloat16(v.z);
        out[i+3] = __float2bfloat16(v.w);
    } else {
        for (int j = i; j < n; ++j) out[j] = __float2bfloat16(in[j]);
    }
}

// ======================= im2row: x[B,3,512,512] -> Pm[16384][768] bf16 =======================
__global__ __launch_bounds__(256) void im2row_kernel(
    const float* __restrict__ x, bf16* __restrict__ Pm)
{
    size_t idx = ((size_t)blockIdx.x * 256 + threadIdx.x) * 8;  // 12,582,912 / 8 = 1,572,864 threads
    int kk = (int)(idx % KPATCH);
    int m  = (int)(idx / KPATCH);
    int b = m >> 10, p = m & 1023;
    int c = kk >> 8, rem = kk & 255, py = rem >> 4, px = rem & 15;  // px in {0,8}
    int pi = p >> 5, pj = p & 31;
    const float* src = &x[(((size_t)b * 3 + c) * 512 + pi * 16 + py) * 512 + pj * 16 + px];
    float4 a0 = *(const float4*)src;
    float4 a1 = *(const float4*)(src + 4);
    bf16 tmp[8];
    tmp[0] = __float2bfloat16(a0.x); tmp[1] = __float2bfloat16(a0.y);
    tmp[2] = __float2bfloat16(a0.z); tmp[3] = __float2bfloat16(a0.w);
    tmp[4] = __float2bfloat16(a1.x); tmp[5] = __float2bfloat16(a1.y);
    tmp[6] = __float2bfloat16(a1.z); tmp[7] = __float2bfloat16(a1.w);
    *(bh8*)&Pm[idx] = *(bh8*)tmp;
}

// ======================= fill cls rows: h[b][0][:] = cls + pos[0] =======================
__global__ __launch_bounds__(384) void fill_cls_kernel(
    const float* __restrict__ cls, const float* __restrict__ pos, float* __restrict__ h)
{
    h[(size_t)blockIdx.x * SS * HH + threadIdx.x] = cls[threadIdx.x] + pos[threadIdx.x];
}

// ======================= LayerNorm (fp32 in -> bf16 out) =======================
__global__ __launch_bounds__(256) void ln_kernel(
    const float* __restrict__ x, const float* __restrict__ w,
    const float* __restrict__ b, bf16* __restrict__ out, int nrows)
{
    int wave = threadIdx.x >> 6;
    int lane = threadIdx.x & 63;
    int row = blockIdx.x * 4 + wave;
    if (row >= nrows) return;
    const float* xr = x + (size_t)row * HH;
    float vals[6];
    float s = 0.f;
    #pragma unroll
    for (int i = 0; i < 6; ++i) { vals[i] = xr[lane + 64 * i]; s += vals[i]; }
    #pragma unroll
    for (int mask = 32; mask >= 1; mask >>= 1) s += __shfl_xor(s, mask);
    float mean = s * (1.f / HH);
    float vs = 0.f;
    #pragma unroll
    for (int i = 0; i < 6; ++i) { float d = vals[i] - mean; vs += d * d; }
    #pragma unroll
    for (int mask = 32; mask >= 1; mask >>= 1) vs += __shfl_xor(vs, mask);
    float rstd = rsqrtf(vs * (1.f / HH) + 1e-5f);
    bf16* outr = out + (size_t)row * HH;
    #pragma unroll
    for (int i = 0; i < 6; ++i) {
        int jj = lane + 64 * i;
        outr[jj] = __float2bfloat16((vals[i] - mean) * rstd * w[jj] + b[jj]);
    }
}

// ======================= MFMA GEMM: A[M][K]bf16 x Bt[N][K]bf16 =======================
// MODE 0: out bf16 = acc + bias            (QKV)
// MODE 1: out bf16 = gelu(acc + bias)      (MLP1)
// MODE 2: out f32  = acc + bias + res      (O-proj / MLP2, res = h in-place)
// MODE 3: patch embed: out f32 h rows b*1025+1+p = acc + bias + pos[1+p]
#define GBM 128
#define GBN 64
#define GBK 64
#define LDK 72   // padded K stride (bf16 elems); 144B rows, 16B aligned

template<int MODE>
__global__ __launch_bounds__(256) void gemm_bt_kernel(
    const bf16* __restrict__ A, const bf16* __restrict__ Bt,
    const float* __restrict__ bias, const float* __restrict__ res,
    void* __restrict__ out, int M, int N, int K)
{
    __shared__ bf16 As[GBM * LDK];
    __shared__ bf16 Bs[GBN * LDK];

    int t = threadIdx.x;
    int w = t >> 6, lane = t & 63;
    int quad = lane >> 4, l15 = lane & 15;
    int bm = blockIdx.x * GBM, bn = blockIdx.y * GBN;
    int wm = (w >> 1) * 64;   // wave row band
    int wn = (w & 1) * 32;    // wave col band

    int arow = t >> 3;          // 0..31
    int acol = (t & 7) * 8;     // 0..56

    f4x acc[4][2];
    #pragma unroll
    for (int i = 0; i < 4; ++i)
        #pragma unroll
        for (int j = 0; j < 2; ++j) acc[i][j] = 0.f;

    for (int k0 = 0; k0 < K; k0 += GBK) {
        // stage A tile: 128 rows x 64 cols
        #pragma unroll
        for (int p = 0; p < 4; ++p) {
            int r = arow + 32 * p;
            int gm = bm + r;
            bh8 val;
            if (gm < M) val = *(const bh8*)&A[(size_t)gm * K + k0 + acol];
            else        val = (bh8){0,0,0,0,0,0,0,0};
            *(bh8*)&As[r * LDK + acol] = val;
        }
        // stage B tile: 64 rows x 64 cols  (N always multiple of 64)
        #pragma unroll
        for (int p = 0; p < 2; ++p) {
            int r = arow + 32 * p;
            bh8 val = *(const bh8*)&Bt[(size_t)(bn + r) * K + k0 + acol];
            *(bh8*)&Bs[r * LDK + acol] = val;
        }
        __syncthreads();

        #pragma unroll
        for (int kc = 0; kc < 2; ++kc) {
            bh8 bfrag[2];
            #pragma unroll
            for (int nf = 0; nf < 2; ++nf)
                bfrag[nf] = *(const bh8*)&Bs[(wn + nf * 16 + l15) * LDK + kc * 32 + quad * 8];
            #pragma unroll
            for (int mf = 0; mf < 4; ++mf) {
                bh8 afrag = *(const bh8*)&As[(wm + mf * 16 + l15) * LDK + kc * 32 + quad * 8];
                #pragma unroll
                for (int nf = 0; nf < 2; ++nf)
                    acc[mf][nf] = __builtin_amdgcn_mfma_f32_16x16x32_bf16(
                        afrag, bfrag[nf], acc[mf][nf], 0, 0, 0);
            }
        }
        __syncthreads();
    }

    // epilogue
    #pragma unroll
    for (int mf = 0; mf < 4; ++mf) {
        #pragma unroll
        for (int nf = 0; nf < 2; ++nf) {
            f4x v = acc[mf][nf];
            int col = bn + wn + nf * 16 + l15;
            float bsv = bias[col];
            #pragma unroll
            for (int r = 0; r < 4; ++r) {
                int row = bm + wm + mf * 16 + quad * 4 + r;
                float val = v[r] + bsv;
                if (MODE == 0) {
                    if (row < M) ((bf16*)out)[(size_t)row * N + col] = __float2bfloat16(val);
                } else if (MODE == 1) {
                    float u = val;
                    float z = 0.7978845608028654f * (u + 0.044715f * u * u * u);
                    z = fminf(fmaxf(z, -15.f), 15.f);
                    float e = __expf(2.f * z);
                    float g = 0.5f * u * (1.f + (e - 1.f) / (e + 1.f));
                    if (row < M) ((bf16*)out)[(size_t)row * N + col] = __float2bfloat16(g);
                } else if (MODE == 2) {
                    if (row < M) {
                        float* o = (float*)out;
                        o[(size_t)row * N + col] = val + res[(size_t)row * N + col];
                    }
                } else {  // MODE 3
                    int b2 = row >> 10, p2 = row & 1023;
                    size_t orow = (size_t)b2 * SS + 1 + p2;
                    ((float*)out)[orow * HH + col] = val + res[(size_t)(1 + p2) * HH + col];
                }
            }
        }
    }
}

// ======================= Fused MFMA attention (flash-style) =======================
// grid (17, NH, B), block 256 (4 waves, 16 q-rows each)
#define ATS 72

__global__ __launch_bounds__(256) void attn_mfma_kernel(
    const bf16* __restrict__ q, const bf16* __restrict__ k,
    const bf16* __restrict__ v, bf16* __restrict__ o)
{
    __shared__ bf16 Qs[64 * ATS];   // aliased as Ps after Q frags are preloaded
    __shared__ bf16 Ks[64 * ATS];
    __shared__ bf16 Vt[64 * ATS];   // V transposed: Vt[d][j]
    bf16* Ps = Qs;

    int t = threadIdx.x, w = t >> 6, lane = t & 63;
    int quad = lane >> 4, l15 = lane & 15;
    int q0 = blockIdx.x * 64;
    int head = blockIdx.y, b = blockIdx.z;
    size_t base = ((size_t)b * SS) * HH + head * DH;

    // stage Q tile (zero-padded)
    {
        int r = t >> 3, c = (t & 7) * 8;
        #pragma unroll
        for (int p = 0; p < 2; ++p) {
            int rr = r + 32 * p, gr = q0 + rr;
            bh8 val;
            if (gr < SS) val = *(const bh8*)&q[base + (size_t)gr * HH + c];
            else         val = (bh8){0,0,0,0,0,0,0,0};
            *(bh8*)&Qs[rr * ATS + c] = val;
        }
    }
    __syncthreads();

    bh8 qfrag[2];
    #pragma unroll
    for (int kc = 0; kc < 2; ++kc)
        qfrag[kc] = *(const bh8*)&Qs[(16 * w + l15) * ATS + kc * 32 + quad * 8];

    f4x oacc[4];
    #pragma unroll
    for (int i = 0; i < 4; ++i) oacc[i] = 0.f;
    float m_run[4], l_run[4];
    #pragma unroll
    for (int r = 0; r < 4; ++r) { m_run[r] = -1e30f; l_run[r] = 0.f; }

    for (int c0 = 0; c0 < SS; c0 += 64) {
        __syncthreads();   // also drains Q-frag reads before Ps(=Qs) writes
        // stage K tile and V^T tile (zero-padded)
        {
            int r = t >> 3, c = (t & 7) * 8;
            #pragma unroll
            for (int p = 0; p < 2; ++p) {
                int rr = r + 32 * p, gr = c0 + rr;
                bh8 kv, vv;
                if (gr < SS) {
                    kv = *(const bh8*)&k[base + (size_t)gr * HH + c];
                    vv = *(const bh8*)&v[base + (size_t)gr * HH + c];
                } else {
                    kv = (bh8){0,0,0,0,0,0,0,0};
                    vv = (bh8){0,0,0,0,0,0,0,0};
                }
                *(bh8*)&Ks[rr * ATS + c] = kv;
                bf16* vp = (bf16*)&vv;
                #pragma unroll
                for (int j = 0; j < 8; ++j) Vt[(c + j) * ATS + rr] = vp[j];
            }
        }
        __syncthreads();

        // S = (Q K^T) * scale
        f4x s[4];
        #pragma unroll
        for (int nf = 0; nf < 4; ++nf) {
            s[nf] = 0.f;
            #pragma unroll
            for (int kc = 0; kc < 2; ++kc) {
                bh8 kf = *(const bh8*)&Ks[(nf * 16 + l15) * ATS + kc * 32 + quad * 8];
                s[nf] = __builtin_amdgcn_mfma_f32_16x16x32_bf16(qfrag[kc], kf, s[nf], 0, 0, 0);
            }
            int cc = c0 + nf * 16 + l15;
            bool ok = cc < SS;
            #pragma unroll
            for (int r = 0; r < 4; ++r)
                s[nf][r] = ok ? s[nf][r] * 0.125f : -1e30f;
        }

        // online softmax over this 64-col tile
        float mnew[4];
        #pragma unroll
        for (int r = 0; r < 4; ++r) {
            float m0 = fmaxf(fmaxf(s[0][r], s[1][r]), fmaxf(s[2][r], s[3][r]));
            #pragma unroll
            for (int mask = 8; mask >= 1; mask >>= 1)
                m0 = fmaxf(m0, __shfl_xor(m0, mask));
            mnew[r] = m0;
        }
        float al[4];
        #pragma unroll
        for (int r = 0; r < 4; ++r) {
            float mn = fmaxf(m_run[r], mnew[r]);
            al[r] = __expf(m_run[r] - mn);
            m_run[r] = mn;
        }
        float rs[4] = {0.f, 0.f, 0.f, 0.f};
        #pragma unroll
        for (int nf = 0; nf < 4; ++nf)
            #pragma unroll
            for (int r = 0; r < 4; ++r) {
                float p = __expf(s[nf][r] - m_run[r]);
                s[nf][r] = p;
                rs[r] += p;
            }
        #pragma unroll
        for (int r = 0; r < 4; ++r) {
            float t0 = rs[r];
            #pragma unroll
            for (int mask = 8; mask >= 1; mask >>= 1)
                t0 += __shfl_xor(t0, mask);
            l_run[r] = l_run[r] * al[r] + t0;
        }
        #pragma unroll
        for (int nf2 = 0; nf2 < 4; ++nf2)
            #pragma unroll
            for (int r = 0; r < 4; ++r)
                oacc[nf2][r] *= al[r];

        // P -> LDS (own wave's 16-row band only)
        #pragma unroll
        for (int nf = 0; nf < 4; ++nf)
            #pragma unroll
            for (int r = 0; r < 4; ++r)
                Ps[(16 * w + quad * 4 + r) * ATS + nf * 16 + l15] = __float2bfloat16(s[nf][r]);

        // O += P V
        #pragma unroll
        for (int nf2 = 0; nf2 < 4; ++nf2)
            #pragma unroll
            for (int kc = 0; kc < 2; ++kc) {
                bh8 pf = *(const bh8*)&Ps[(16 * w + l15) * ATS + kc * 32 + quad * 8];
                bh8 vf = *(const bh8*)&Vt[(nf2 * 16 + l15) * ATS + kc * 32 + quad * 8];
                oacc[nf2] = __builtin_amdgcn_mfma_f32_16x16x32_bf16(pf, vf, oacc[nf2], 0, 0, 0);
            }
    }

    // write O (normalized) as bf16
    #pragma unroll
    for (int nf2 = 0; nf2 < 4; ++nf2)
        #pragma unroll
        for (int r = 0; r < 4; ++r) {
            int row = q0 + 16 * w + quad * 4 + r;
            if (row < SS)
                o[base + (size_t)row * HH + nf2 * 16 + l15] =
                    __float2bfloat16(oacc[nf2][r] / l_run[r]);
        }
}

// ======================= Classifier (fp32) =======================
__global__ __launch_bounds__(256) void cls_kernel(
    const float* __restrict__ h, const float* __restrict__ wc,
    const float* __restrict__ bc, float* __restrict__ out)
{
    __shared__ float hr[HH];
    int b = blockIdx.x, t = threadIdx.x;
    for (int i = t; i < HH; i += 256) hr[i] = h[(size_t)b * SS * HH + i];
    __syncthreads();
    for (int n = t; n < NC; n += 256) {
        float acc = bc[n];
        #pragma unroll 4
        for (int kk = 0; kk < HH; ++kk) acc += hr[kk] * wc[(size_t)kk * NC + n];
        out[b * NC + n] = acc;
    }
}

// ======================= Launch =======================
extern "C" void kernel_launch(void* const* d_in, const int* in_sizes, int n_in,
                              void* d_out, int out_size, void* d_ws, size_t ws_size,
                              hipStream_t stream) {
    const float* x        = (const float*)d_in[0];
    const float* conv_w   = (const float*)d_in[1];
    const float* conv_b   = (const float*)d_in[2];
    const float* cls_tok  = (const float*)d_in[3];
    const float* pos_emb  = (const float*)d_in[4];
    const float* ln1_w    = (const float*)d_in[5];
    const float* ln1_b    = (const float*)d_in[6];
    const float* wq       = (const float*)d_in[7];
    const float* bq       = (const float*)d_in[8];
    const float* wk       = (const float*)d_in[9];
    const float* bk       = (const float*)d_in[10];
    const float* wv       = (const float*)d_in[11];
    const float* bv       = (const float*)d_in[12];
    const float* wo       = (const float*)d_in[13];
    const float* bo       = (const float*)d_in[14];
    const float* ln2_w    = (const float*)d_in[15];
    const float* ln2_b    = (const float*)d_in[16];
    const float* w1       = (const float*)d_in[17];
    const float* b1       = (const float*)d_in[18];
    const float* w2       = (const float*)d_in[19];
    const float* b2       = (const float*)d_in[20];
    const float* wc       = (const float*)d_in[21];
    const float* bc       = (const float*)d_in[22];
    float* out = (float*)d_out;

    const size_t BSH = (size_t)BB * SS * HH;   // 6,297,600
    char* wp = (char*)d_ws;
    float* h  = (float*)wp;            wp += BSH * 4;
    bf16* hn  = (bf16*)wp;             wp += BSH * 2;
    bf16* qb  = (bf16*)wp;             wp += BSH * 2;
    bf16* kb  = (bf16*)wp;             wp += BSH * 2;
    bf16* vb  = (bf16*)wp;             wp += BSH * 2;
    bf16* tb  = (bf16*)wp;             wp += BSH * 2;
    bf16* mb  = qb;                    // MLP intermediate aliases q..t (B*S*I bf16)
    bf16* Pm  = qb;                    // patch matrix aliases q region (pre-QKV)
    bf16* wqt = (bf16*)wp;             wp += (size_t)LL * HH * HH * 2;
    bf16* wkt = (bf16*)wp;             wp += (size_t)LL * HH * HH * 2;
    bf16* wvt = (bf16*)wp;             wp += (size_t)LL * HH * HH * 2;
    bf16* wot = (bf16*)wp;             wp += (size_t)LL * HH * HH * 2;
    bf16* w1t = (bf16*)wp;             wp += (size_t)LL * HH * II * 2;
    bf16* w2t = (bf16*)wp;             wp += (size_t)LL * II * HH * 2;
    bf16* cwb = (bf16*)wp;             wp += (size_t)HH * KPATCH * 2;

    // weight prep
    dim3 tcb(256);
    transpose_cast_kernel<<<dim3(12, 12, LL), tcb, 0, stream>>>(wq, wqt, HH, HH);
    transpose_cast_kernel<<<dim3(12, 12, LL), tcb, 0, stream>>>(wk, wkt, HH, HH);
    transpose_cast_kernel<<<dim3(12, 12, LL), tcb, 0, stream>>>(wv, wvt, HH, HH);
    transpose_cast_kernel<<<dim3(12, 12, LL), tcb, 0, stream>>>(wo, wot, HH, HH);
    transpose_cast_kernel<<<dim3(48, 12, LL), tcb, 0, stream>>>(w1, w1t, HH, II);
    transpose_cast_kernel<<<dim3(12, 48, LL), tcb, 0, stream>>>(w2, w2t, II, HH);
    cast_kernel<<<288, 256, 0, stream>>>(conv_w, cwb, HH * KPATCH);  // already [N][K] layout

    // patch embed as GEMM
    im2row_kernel<<<6144, 256, 0, stream>>>(x, Pm);
    gemm_bt_kernel<3><<<dim3(128, 6), 256, 0, stream>>>(
        Pm, cwb, conv_b, pos_emb, h, MPATCH, HH, KPATCH);
    fill_cls_kernel<<<BB, 384, 0, stream>>>(cls_tok, pos_emb, h);

    const int M = MROWS;
    dim3 gH(129, HH / GBN);    // N=384
    dim3 gI(129, II / GBN);    // N=1536

    for (int l = 0; l < LL; ++l) {
        const float* l1w = ln1_w + (size_t)l * HH;
        const float* l1b = ln1_b + (size_t)l * HH;
        const float* l2w = ln2_w + (size_t)l * HH;
        const float* l2b = ln2_b + (size_t)l * HH;
        const bf16* wq_l = wqt + (size_t)l * HH * HH;
        const bf16* wk_l = wkt + (size_t)l * HH * HH;
        const bf16* wv_l = wvt + (size_t)l * HH * HH;
        const bf16* wo_l = wot + (size_t)l * HH * HH;
        const bf16* w1_l = w1t + (size_t)l * HH * II;
        const bf16* w2_l = w2t + (size_t)l * II * HH;
        const float* bq_l = bq + (size_t)l * HH;
        const float* bk_l = bk + (size_t)l * HH;
        const float* bv_l = bv + (size_t)l * HH;
        const float* bo_l = bo + (size_t)l * HH;
        const float* b1_l = b1 + (size_t)l * II;
        const float* b2_l = b2 + (size_t)l * HH;

        ln_kernel<<<4100, 256, 0, stream>>>(h, l1w, l1b, hn, M);

        gemm_bt_kernel<0><<<gH, 256, 0, stream>>>(hn, wq_l, bq_l, nullptr, qb, M, HH, HH);
        gemm_bt_kernel<0><<<gH, 256, 0, stream>>>(hn, wk_l, bk_l, nullptr, kb, M, HH, HH);
        gemm_bt_kernel<0><<<gH, 256, 0, stream>>>(hn, wv_l, bv_l, nullptr, vb, M, HH, HH);

        attn_mfma_kernel<<<dim3(17, NHEAD, BB), 256, 0, stream>>>(qb, kb, vb, tb);

        gemm_bt_kernel<2><<<gH, 256, 0, stream>>>(tb, wo_l, bo_l, h, h, M, HH, HH);

        ln_kernel<<<4100, 256, 0, stream>>>(h, l2w, l2b, hn, M);

        gemm_bt_kernel<1><<<gI, 256, 0, stream>>>(hn, w1_l, b1_l, nullptr, mb, M, II, HH);
        gemm_bt_kernel<2><<<gH, 256, 0, stream>>>(mb, w2_l, b2_l, h, h, M, HH, II);
    }

    cls_kernel<<<BB, 256, 0, stream>>>(h, wc, bc, out);
}

// Round 3
// 4347.199 us; speedup vs baseline: 14.3681x; 1.2433x over previous
//
#include <hip/hip_runtime.h>
#include <hip/hip_bf16.h>
#include <math.h>

// ---- Model constants ----
#define BB 16
#define HH 384
#define NHEAD 6
#define DH 64
#define LL 12
#define II 1536
#define NC 1000
#define SS 1025
#define MROWS (BB * SS)      // 16400
#define MPAD  16512          // MROWS padded to multiple of 128
#define KPATCH 768           // 3*16*16
#define MPATCH (BB * 1024)   // 16384
#define QS 1152              // fused qkv row stride

typedef __hip_bfloat16 bf16;
typedef __attribute__((ext_vector_type(8))) short bh8;   // 8 bf16 (MFMA A/B frag)
typedef __attribute__((ext_vector_type(4))) float f4x;   // MFMA C/D frag

__device__ __forceinline__ void gload16(const bf16* g, bf16* l) {
    __builtin_amdgcn_global_load_lds(
        (const __attribute__((address_space(1))) unsigned int*)g,
        (__attribute__((address_space(3))) unsigned int*)l, 16, 0, 0);
}

// ======================= transpose + cast: [L][K][N] f32 -> [L][N][K] bf16 =======================
__global__ __launch_bounds__(256) void transpose_cast_kernel(
    const float* __restrict__ in, bf16* __restrict__ out, int K, int N, int ostride)
{
    __shared__ float tile[32][33];
    int l = blockIdx.z;
    const float* ip = in + (size_t)l * K * N;
    bf16* op = out + (size_t)l * ostride;
    int n0 = blockIdx.x * 32, k0 = blockIdx.y * 32;
    int tx = threadIdx.x & 31, ty = threadIdx.x >> 5;   // 32 x 8
    #pragma unroll
    for (int i = 0; i < 32; i += 8)
        tile[ty + i][tx] = ip[(size_t)(k0 + ty + i) * N + n0 + tx];
    __syncthreads();
    #pragma unroll
    for (int i = 0; i < 32; i += 8)
        op[(size_t)(n0 + ty + i) * K + k0 + tx] = __float2bfloat16(tile[tx][ty + i]);
}

// ======================= plain cast f32 -> bf16 =======================
__global__ __launch_bounds__(256) void cast_kernel(
    const float* __restrict__ in, bf16* __restrict__ out, int n)
{
    int i = blockIdx.x * 1024 + threadIdx.x * 4;
    if (i + 3 < n) {
        float4 v = *(const float4*)&in[i];
        out[i]   = __float2bfloat16(v.x);
        out[i+1] = __float2bfloat16(v.y);
        out[i+2] = __float2bfloat16(v.z);
        out[i+3] = __float2bfloat16(v.w);
    } else {
        for (int j = i; j < n; ++j) out[j] = __float2bfloat16(in[j]);
    }
}

// ======================= concat qkv biases: cb[l][1152] =======================
__global__ __launch_bounds__(384) void bias_concat_kernel(
    const float* __restrict__ bq, const float* __restrict__ bk,
    const float* __restrict__ bv, float* __restrict__ cb)
{
    int l = blockIdx.x, t = threadIdx.x;
    cb[l * QS + t]       = bq[l * HH + t];
    cb[l * QS + 384 + t] = bk[l * HH + t];
    cb[l * QS + 768 + t] = bv[l * HH + t];
}

// ======================= im2row: x[B,3,512,512] -> Pm[16384][768] bf16 =======================
__global__ __launch_bounds__(256) void im2row_kernel(
    const float* __restrict__ x, bf16* __restrict__ Pm)
{
    size_t idx = ((size_t)blockIdx.x * 256 + threadIdx.x) * 8;
    int kk = (int)(idx % KPATCH);
    int m  = (int)(idx / KPATCH);
    int b = m >> 10, p = m & 1023;
    int c = kk >> 8, rem = kk & 255, py = rem >> 4, px = rem & 15;
    int pi = p >> 5, pj = p & 31;
    const float* src = &x[(((size_t)b * 3 + c) * 512 + pi * 16 + py) * 512 + pj * 16 + px];
    float4 a0 = *(const float4*)src;
    float4 a1 = *(const float4*)(src + 4);
    bf16 tmp[8];
    tmp[0] = __float2bfloat16(a0.x); tmp[1] = __float2bfloat16(a0.y);
    tmp[2] = __float2bfloat16(a0.z); tmp[3] = __float2bfloat16(a0.w);
    tmp[4] = __float2bfloat16(a1.x); tmp[5] = __float2bfloat16(a1.y);
    tmp[6] = __float2bfloat16(a1.z); tmp[7] = __float2bfloat16(a1.w);
    *(bh8*)&Pm[idx] = *(bh8*)tmp;
}

// ======================= fill cls rows =======================
__global__ __launch_bounds__(384) void fill_cls_kernel(
    const float* __restrict__ cls, const float* __restrict__ pos, float* __restrict__ h)
{
    h[(size_t)blockIdx.x * SS * HH + threadIdx.x] = cls[threadIdx.x] + pos[threadIdx.x];
}

// ======================= LayerNorm (fp32 in -> bf16 out) =======================
__global__ __launch_bounds__(256) void ln_kernel(
    const float* __restrict__ x, const float* __restrict__ w,
    const float* __restrict__ b, bf16* __restrict__ out, int nrows)
{
    int wave = threadIdx.x >> 6;
    int lane = threadIdx.x & 63;
    int row = blockIdx.x * 4 + wave;
    if (row >= nrows) return;
    const float* xr = x + (size_t)row * HH;
    float vals[6];
    float s = 0.f;
    #pragma unroll
    for (int i = 0; i < 6; ++i) { vals[i] = xr[lane + 64 * i]; s += vals[i]; }
    #pragma unroll
    for (int mask = 32; mask >= 1; mask >>= 1) s += __shfl_xor(s, mask);
    float mean = s * (1.f / HH);
    float vs = 0.f;
    #pragma unroll
    for (int i = 0; i < 6; ++i) { float d = vals[i] - mean; vs += d * d; }
    #pragma unroll
    for (int mask = 32; mask >= 1; mask >>= 1) vs += __shfl_xor(vs, mask);
    float rstd = rsqrtf(vs * (1.f / HH) + 1e-5f);
    bf16* outr = out + (size_t)row * HH;
    #pragma unroll
    for (int i = 0; i < 6; ++i) {
        int jj = lane + 64 * i;
        outr[jj] = __float2bfloat16((vals[i] - mean) * rstd * w[jj] + b[jj]);
    }
}

// ======================= MFMA GEMM v2 (m97-style) =======================
// A[M][K]bf16 x Bt[N][K]bf16; 128x128 tile, GBK=64, global_load_lds + XOR swizzle.
// MODE 0: out bf16 = acc + bias
// MODE 1: out bf16 = gelu(acc + bias)
// MODE 2: out f32  = acc + bias + res[row*N+col]
// MODE 3: patch embed scatter: h[b*SS+1+p][col] = acc + bias + pos[(1+p)*HH+col]
template<int MODE>
__global__ __launch_bounds__(256) void gemm_v2_kernel(
    const bf16* __restrict__ A, const bf16* __restrict__ Bt,
    const float* __restrict__ bias, const float* __restrict__ res,
    void* __restrict__ out, int M, int N, int K)
{
    __shared__ bf16 As[128 * 64];
    __shared__ bf16 Bs[128 * 64];

    int t = threadIdx.x;
    int w = t >> 6, lane = t & 63;
    int quad = lane >> 4, l15 = lane & 15;
    int bm = blockIdx.x * 128, bn = blockIdx.y * 128;
    int wm = (w >> 1) * 64, wn = (w & 1) * 64;

    int srow = lane >> 3;       // 0..7: row within 8-row staging chunk
    int scol = lane & 7;        // physical col-block written by this lane

    f4x acc[4][4];
    #pragma unroll
    for (int i = 0; i < 4; ++i)
        #pragma unroll
        for (int j = 0; j < 4; ++j) acc[i][j] = 0.f;

    for (int k0 = 0; k0 < K; k0 += 64) {
        // stage A: 16 chunks of 8 rows; wave w takes chunks 4w..4w+3
        #pragma unroll
        for (int p = 0; p < 4; ++p) {
            int c = w * 4 + p;
            int r = c * 8 + srow;
            int gcb = scol ^ (r & 7);           // XOR swizzle via source permute
            gload16(A + (size_t)(bm + r) * K + k0 + gcb * 8, &As[c * 8 * 64]);
        }
        #pragma unroll
        for (int p = 0; p < 4; ++p) {
            int c = w * 4 + p;
            int r = c * 8 + srow;
            int gcb = scol ^ (r & 7);
            gload16(Bt + (size_t)(bn + r) * K + k0 + gcb * 8, &Bs[c * 8 * 64]);
        }
        __syncthreads();

        #pragma unroll
        for (int kc = 0; kc < 2; ++kc) {
            bh8 bfr[4];
            #pragma unroll
            for (int nf = 0; nf < 4; ++nf) {
                int rn = wn + nf * 16 + l15;
                int pcb = (kc * 4 + quad) ^ (rn & 7);
                bfr[nf] = *(const bh8*)&Bs[rn * 64 + pcb * 8];
            }
            #pragma unroll
            for (int mf = 0; mf < 4; ++mf) {
                int rm = wm + mf * 16 + l15;
                int pcb = (kc * 4 + quad) ^ (rm & 7);
                bh8 afr = *(const bh8*)&As[rm * 64 + pcb * 8];
                #pragma unroll
                for (int nf = 0; nf < 4; ++nf)
                    acc[mf][nf] = __builtin_amdgcn_mfma_f32_16x16x32_bf16(
                        afr, bfr[nf], acc[mf][nf], 0, 0, 0);
            }
        }
        __syncthreads();
    }

    #pragma unroll
    for (int mf = 0; mf < 4; ++mf) {
        #pragma unroll
        for (int nf = 0; nf < 4; ++nf) {
            f4x v = acc[mf][nf];
            int col = bn + wn + nf * 16 + l15;
            float bsv = bias[col];
            #pragma unroll
            for (int r = 0; r < 4; ++r) {
                int row = bm + wm + mf * 16 + quad * 4 + r;
                float val = v[r] + bsv;
                if (MODE == 0) {
                    if (row < M) ((bf16*)out)[(size_t)row * N + col] = __float2bfloat16(val);
                } else if (MODE == 1) {
                    float u = val;
                    float z = 0.7978845608028654f * (u + 0.044715f * u * u * u);
                    z = fminf(fmaxf(z, -15.f), 15.f);
                    float e = __expf(2.f * z);
                    float g = 0.5f * u * (1.f + (e - 1.f) / (e + 1.f));
                    if (row < M) ((bf16*)out)[(size_t)row * N + col] = __float2bfloat16(g);
                } else if (MODE == 2) {
                    if (row < M) {
                        float* o = (float*)out;
                        o[(size_t)row * N + col] = val + res[(size_t)row * N + col];
                    }
                } else {  // MODE 3
                    int b2 = row >> 10, p2 = row & 1023;
                    size_t orow = (size_t)b2 * SS + 1 + p2;
                    ((float*)out)[orow * HH + col] = val + res[(size_t)(1 + p2) * HH + col];
                }
            }
        }
    }
}

// ======================= Fused MFMA attention (flash-style) =======================
// grid (17, NH, B), block 256 (4 waves, 16 q-rows each). qkv fused buffer, stride QS.
#define ATS 72

__global__ __launch_bounds__(256) void attn_mfma_kernel(
    const bf16* __restrict__ qkv, bf16* __restrict__ o)
{
    __shared__ bf16 Qs[64 * ATS];
    __shared__ bf16 Ks[64 * ATS];
    __shared__ bf16 Vt[64 * ATS];
    bf16* Ps = Qs;

    int t = threadIdx.x, w = t >> 6, lane = t & 63;
    int quad = lane >> 4, l15 = lane & 15;
    int q0 = blockIdx.x * 64;
    int head = blockIdx.y, b = blockIdx.z;
    size_t base  = ((size_t)b * SS) * QS + head * DH;   // q at +0, k at +384, v at +768
    size_t obase = ((size_t)b * SS) * HH + head * DH;

    {
        int r = t >> 3, c = (t & 7) * 8;
        #pragma unroll
        for (int p = 0; p < 2; ++p) {
            int rr = r + 32 * p, gr = q0 + rr;
            bh8 val;
            if (gr < SS) val = *(const bh8*)&qkv[base + (size_t)gr * QS + c];
            else         val = (bh8){0,0,0,0,0,0,0,0};
            *(bh8*)&Qs[rr * ATS + c] = val;
        }
    }
    __syncthreads();

    bh8 qfrag[2];
    #pragma unroll
    for (int kc = 0; kc < 2; ++kc)
        qfrag[kc] = *(const bh8*)&Qs[(16 * w + l15) * ATS + kc * 32 + quad * 8];

    f4x oacc[4];
    #pragma unroll
    for (int i = 0; i < 4; ++i) oacc[i] = 0.f;
    float m_run[4], l_run[4];
    #pragma unroll
    for (int r = 0; r < 4; ++r) { m_run[r] = -1e30f; l_run[r] = 0.f; }

    for (int c0 = 0; c0 < SS; c0 += 64) {
        __syncthreads();
        {
            int r = t >> 3, c = (t & 7) * 8;
            #pragma unroll
            for (int p = 0; p < 2; ++p) {
                int rr = r + 32 * p, gr = c0 + rr;
                bh8 kv, vv;
                if (gr < SS) {
                    kv = *(const bh8*)&qkv[base + 384 + (size_t)gr * QS + c];
                    vv = *(const bh8*)&qkv[base + 768 + (size_t)gr * QS + c];
                } else {
                    kv = (bh8){0,0,0,0,0,0,0,0};
                    vv = (bh8){0,0,0,0,0,0,0,0};
                }
                *(bh8*)&Ks[rr * ATS + c] = kv;
                bf16* vp = (bf16*)&vv;
                #pragma unroll
                for (int j = 0; j < 8; ++j) Vt[(c + j) * ATS + rr] = vp[j];
            }
        }
        __syncthreads();

        f4x s[4];
        #pragma unroll
        for (int nf = 0; nf < 4; ++nf) {
            s[nf] = 0.f;
            #pragma unroll
            for (int kc = 0; kc < 2; ++kc) {
                bh8 kf = *(const bh8*)&Ks[(nf * 16 + l15) * ATS + kc * 32 + quad * 8];
                s[nf] = __builtin_amdgcn_mfma_f32_16x16x32_bf16(qfrag[kc], kf, s[nf], 0, 0, 0);
            }
            int cc = c0 + nf * 16 + l15;
            bool ok = cc < SS;
            #pragma unroll
            for (int r = 0; r < 4; ++r)
                s[nf][r] = ok ? s[nf][r] * 0.125f : -1e30f;
        }

        float mnew[4];
        #pragma unroll
        for (int r = 0; r < 4; ++r) {
            float m0 = fmaxf(fmaxf(s[0][r], s[1][r]), fmaxf(s[2][r], s[3][r]));
            #pragma unroll
            for (int mask = 8; mask >= 1; mask >>= 1)
                m0 = fmaxf(m0, __shfl_xor(m0, mask));
            mnew[r] = m0;
        }
        float al[4];
        #pragma unroll
        for (int r = 0; r < 4; ++r) {
            float mn = fmaxf(m_run[r], mnew[r]);
            al[r] = __expf(m_run[r] - mn);
            m_run[r] = mn;
        }
        float rs[4] = {0.f, 0.f, 0.f, 0.f};
        #pragma unroll
        for (int nf = 0; nf < 4; ++nf)
            #pragma unroll
            for (int r = 0; r < 4; ++r) {
                float p = __expf(s[nf][r] - m_run[r]);
                s[nf][r] = p;
                rs[r] += p;
            }
        #pragma unroll
        for (int r = 0; r < 4; ++r) {
            float t0 = rs[r];
            #pragma unroll
            for (int mask = 8; mask >= 1; mask >>= 1)
                t0 += __shfl_xor(t0, mask);
            l_run[r] = l_run[r] * al[r] + t0;
        }
        #pragma unroll
        for (int nf2 = 0; nf2 < 4; ++nf2)
            #pragma unroll
            for (int r = 0; r < 4; ++r)
                oacc[nf2][r] *= al[r];

        #pragma unroll
        for (int nf = 0; nf < 4; ++nf)
            #pragma unroll
            for (int r = 0; r < 4; ++r)
                Ps[(16 * w + quad * 4 + r) * ATS + nf * 16 + l15] = __float2bfloat16(s[nf][r]);

        #pragma unroll
        for (int nf2 = 0; nf2 < 4; ++nf2)
            #pragma unroll
            for (int kc = 0; kc < 2; ++kc) {
                bh8 pf = *(const bh8*)&Ps[(16 * w + l15) * ATS + kc * 32 + quad * 8];
                bh8 vf = *(const bh8*)&Vt[(nf2 * 16 + l15) * ATS + kc * 32 + quad * 8];
                oacc[nf2] = __builtin_amdgcn_mfma_f32_16x16x32_bf16(pf, vf, oacc[nf2], 0, 0, 0);
            }
    }

    #pragma unroll
    for (int nf2 = 0; nf2 < 4; ++nf2)
        #pragma unroll
        for (int r = 0; r < 4; ++r) {
            int row = q0 + 16 * w + quad * 4 + r;
            if (row < SS)
                o[obase + (size_t)row * HH + nf2 * 16 + l15] =
                    __float2bfloat16(oacc[nf2][r] / l_run[r]);
        }
}

// ======================= Classifier v2: grid (16 n-chunks, B) =======================
__global__ __launch_bounds__(256) void cls_kernel(
    const float* __restrict__ h, const float* __restrict__ wc,
    const float* __restrict__ bc, float* __restrict__ out)
{
    __shared__ float hr[HH];
    __shared__ float part[4][64];
    int b = blockIdx.y, n0 = blockIdx.x * 64;
    int t = threadIdx.x;
    for (int i = t; i < HH; i += 256) hr[i] = h[(size_t)b * SS * HH + i];
    __syncthreads();
    int nn = t & 63, seg = t >> 6;
    int n = n0 + nn;
    float acc = 0.f;
    if (n < NC) {
        #pragma unroll 4
        for (int kk = seg * 96; kk < seg * 96 + 96; ++kk)
            acc += hr[kk] * wc[(size_t)kk * NC + n];
    }
    part[seg][nn] = acc;
    __syncthreads();
    if (t < 64 && n0 + t < NC)
        out[b * NC + n0 + t] = part[0][t] + part[1][t] + part[2][t] + part[3][t] + bc[n0 + t];
}

// ======================= Launch =======================
extern "C" void kernel_launch(void* const* d_in, const int* in_sizes, int n_in,
                              void* d_out, int out_size, void* d_ws, size_t ws_size,
                              hipStream_t stream) {
    const float* x        = (const float*)d_in[0];
    const float* conv_w   = (const float*)d_in[1];
    const float* conv_b   = (const float*)d_in[2];
    const float* cls_tok  = (const float*)d_in[3];
    const float* pos_emb  = (const float*)d_in[4];
    const float* ln1_w    = (const float*)d_in[5];
    const float* ln1_b    = (const float*)d_in[6];
    const float* wq       = (const float*)d_in[7];
    const float* bq       = (const float*)d_in[8];
    const float* wk       = (const float*)d_in[9];
    const float* bk       = (const float*)d_in[10];
    const float* wv       = (const float*)d_in[11];
    const float* bv       = (const float*)d_in[12];
    const float* wo       = (const float*)d_in[13];
    const float* bo       = (const float*)d_in[14];
    const float* ln2_w    = (const float*)d_in[15];
    const float* ln2_b    = (const float*)d_in[16];
    const float* w1       = (const float*)d_in[17];
    const float* b1       = (const float*)d_in[18];
    const float* w2       = (const float*)d_in[19];
    const float* b2       = (const float*)d_in[20];
    const float* wc       = (const float*)d_in[21];
    const float* bc       = (const float*)d_in[22];
    float* out = (float*)d_out;

    char* wp = (char*)d_ws;
    float* h   = (float*)wp;  wp += (size_t)MROWS * HH * 4;          // 25.2 MB
    bf16* hn   = (bf16*)wp;   wp += (size_t)MPAD * HH * 2;           // 12.7 MB (padded A)
    bf16* tb   = (bf16*)wp;   wp += (size_t)MPAD * HH * 2;           // 12.7 MB (padded A)
    bf16* mb   = (bf16*)wp;   wp += (size_t)MPAD * II * 2;           // 50.7 MB (padded A)
    bf16* qkvb = mb;          // qkv [MROWS][1152] aliases mb (disjoint lifetimes)
    bf16* Pm   = mb;          // patch matrix aliases mb too
    bf16* wqkv = (bf16*)wp;   wp += (size_t)LL * QS * HH * 2;        // 10.6 MB
    bf16* wot  = (bf16*)wp;   wp += (size_t)LL * HH * HH * 2;        // 3.5 MB
    bf16* w1t  = (bf16*)wp;   wp += (size_t)LL * HH * II * 2;        // 14.2 MB
    bf16* w2t  = (bf16*)wp;   wp += (size_t)LL * II * HH * 2;        // 14.2 MB
    bf16* cwb  = (bf16*)wp;   wp += (size_t)HH * KPATCH * 2;         // 0.6 MB
    float* cbias = (float*)wp; wp += (size_t)LL * QS * 4;            // 55 KB

    // ---- weight prep ----
    transpose_cast_kernel<<<dim3(12, 12, LL), 256, 0, stream>>>(wq, wqkv,          HH, HH, QS * HH);
    transpose_cast_kernel<<<dim3(12, 12, LL), 256, 0, stream>>>(wk, wqkv + 147456, HH, HH, QS * HH);
    transpose_cast_kernel<<<dim3(12, 12, LL), 256, 0, stream>>>(wv, wqkv + 294912, HH, HH, QS * HH);
    transpose_cast_kernel<<<dim3(12, 12, LL), 256, 0, stream>>>(wo, wot, HH, HH, HH * HH);
    transpose_cast_kernel<<<dim3(48, 12, LL), 256, 0, stream>>>(w1, w1t, HH, II, HH * II);
    transpose_cast_kernel<<<dim3(12, 48, LL), 256, 0, stream>>>(w2, w2t, II, HH, II * HH);
    cast_kernel<<<288, 256, 0, stream>>>(conv_w, cwb, HH * KPATCH);
    bias_concat_kernel<<<LL, 384, 0, stream>>>(bq, bk, bv, cbias);

    // ---- patch embed as GEMM ----
    im2row_kernel<<<6144, 256, 0, stream>>>(x, Pm);
    gemm_v2_kernel<3><<<dim3(128, 3), 256, 0, stream>>>(
        Pm, cwb, conv_b, pos_emb, h, MPATCH, HH, KPATCH);
    fill_cls_kernel<<<BB, 384, 0, stream>>>(cls_tok, pos_emb, h);

    const int M = MROWS;
    dim3 gQKV(129, 9);   // N=1152
    dim3 gH(129, 3);     // N=384
    dim3 gI(129, 12);    // N=1536

    for (int l = 0; l < LL; ++l) {
        const float* l1w = ln1_w + (size_t)l * HH;
        const float* l1b = ln1_b + (size_t)l * HH;
        const float* l2w = ln2_w + (size_t)l * HH;
        const float* l2b = ln2_b + (size_t)l * HH;
        const bf16* wqkv_l = wqkv + (size_t)l * QS * HH;
        const bf16* wo_l   = wot  + (size_t)l * HH * HH;
        const bf16* w1_l   = w1t  + (size_t)l * HH * II;
        const bf16* w2_l   = w2t  + (size_t)l * II * HH;
        const float* cb_l  = cbias + (size_t)l * QS;
        const float* bo_l  = bo + (size_t)l * HH;
        const float* b1_l  = b1 + (size_t)l * II;
        const float* b2_l  = b2 + (size_t)l * HH;

        ln_kernel<<<4100, 256, 0, stream>>>(h, l1w, l1b, hn, M);

        gemm_v2_kernel<0><<<gQKV, 256, 0, stream>>>(hn, wqkv_l, cb_l, nullptr, qkvb, M, QS, HH);

        attn_mfma_kernel<<<dim3(17, NHEAD, BB), 256, 0, stream>>>(qkvb, tb);

        gemm_v2_kernel<2><<<gH, 256, 0, stream>>>(tb, wo_l, bo_l, h, h, M, HH, HH);

        ln_kernel<<<4100, 256, 0, stream>>>(h, l2w, l2b, hn, M);

        gemm_v2_kernel<1><<<gI, 256, 0, stream>>>(hn, w1_l, b1_l, nullptr, mb, M, II, HH);
        gemm_v2_kernel<2><<<gH, 256, 0, stream>>>(mb, w2_l, b2_l, h, h, M, HH, II);
    }

    cls_kernel<<<dim3(16, BB), 256, 0, stream>>>(h, wc, bc, out);
}

// Round 4
// 3967.818 us; speedup vs baseline: 15.7419x; 1.0956x over previous
//
#include <hip/hip_runtime.h>
#include <hip/hip_bf16.h>
#include <math.h>

// ---- Model constants ----
#define BB 16
#define HH 384
#define NHEAD 6
#define DH 64
#define LL 12
#define II 1536
#define NC 1000
#define SS 1025
#define MROWS (BB * SS)      // 16400
#define MPAD  16512          // MROWS padded to multiple of 128
#define KPATCH 768           // 3*16*16
#define MPATCH (BB * 1024)   // 16384
#define QS 1152              // fused qkv row stride
#define SSP 1088             // padded seq stride for V^T (17*64)

typedef __hip_bfloat16 bf16;
typedef __attribute__((ext_vector_type(8))) short bh8;   // 8 bf16 (MFMA A/B frag)
typedef __attribute__((ext_vector_type(4))) float f4x;   // MFMA C/D frag

__device__ __forceinline__ void gload16(const bf16* g, bf16* l) {
    __builtin_amdgcn_global_load_lds(
        (const __attribute__((address_space(1))) unsigned int*)g,
        (__attribute__((address_space(3))) unsigned int*)l, 16, 0, 0);
}

// ======================= transpose + cast: [L][K][N] f32 -> [L][N][K] bf16 =======================
__global__ __launch_bounds__(256) void transpose_cast_kernel(
    const float* __restrict__ in, bf16* __restrict__ out, int K, int N, int ostride)
{
    __shared__ float tile[32][33];
    int l = blockIdx.z;
    const float* ip = in + (size_t)l * K * N;
    bf16* op = out + (size_t)l * ostride;
    int n0 = blockIdx.x * 32, k0 = blockIdx.y * 32;
    int tx = threadIdx.x & 31, ty = threadIdx.x >> 5;   // 32 x 8
    #pragma unroll
    for (int i = 0; i < 32; i += 8)
        tile[ty + i][tx] = ip[(size_t)(k0 + ty + i) * N + n0 + tx];
    __syncthreads();
    #pragma unroll
    for (int i = 0; i < 32; i += 8)
        op[(size_t)(n0 + ty + i) * K + k0 + tx] = __float2bfloat16(tile[tx][ty + i]);
}

// ======================= plain cast f32 -> bf16 =======================
__global__ __launch_bounds__(256) void cast_kernel(
    const float* __restrict__ in, bf16* __restrict__ out, int n)
{
    int i = blockIdx.x * 1024 + threadIdx.x * 4;
    if (i + 3 < n) {
        float4 v = *(const float4*)&in[i];
        out[i]   = __float2bfloat16(v.x);
        out[i+1] = __float2bfloat16(v.y);
        out[i+2] = __float2bfloat16(v.z);
        out[i+3] = __float2bfloat16(v.w);
    } else {
        for (int j = i; j < n; ++j) out[j] = __float2bfloat16(in[j]);
    }
}

// ======================= concat qkv biases: cb[l][1152] =======================
__global__ __launch_bounds__(384) void bias_concat_kernel(
    const float* __restrict__ bq, const float* __restrict__ bk,
    const float* __restrict__ bv, float* __restrict__ cb)
{
    int l = blockIdx.x, t = threadIdx.x;
    cb[l * QS + t]       = bq[l * HH + t];
    cb[l * QS + 384 + t] = bk[l * HH + t];
    cb[l * QS + 768 + t] = bv[l * HH + t];
}

// ======================= im2row: x[B,3,512,512] -> Pm[16384][768] bf16 =======================
__global__ __launch_bounds__(256) void im2row_kernel(
    const float* __restrict__ x, bf16* __restrict__ Pm)
{
    size_t idx = ((size_t)blockIdx.x * 256 + threadIdx.x) * 8;
    int kk = (int)(idx % KPATCH);
    int m  = (int)(idx / KPATCH);
    int b = m >> 10, p = m & 1023;
    int c = kk >> 8, rem = kk & 255, py = rem >> 4, px = rem & 15;
    int pi = p >> 5, pj = p & 31;
    const float* src = &x[(((size_t)b * 3 + c) * 512 + pi * 16 + py) * 512 + pj * 16 + px];
    float4 a0 = *(const float4*)src;
    float4 a1 = *(const float4*)(src + 4);
    bf16 tmp[8];
    tmp[0] = __float2bfloat16(a0.x); tmp[1] = __float2bfloat16(a0.y);
    tmp[2] = __float2bfloat16(a0.z); tmp[3] = __float2bfloat16(a0.w);
    tmp[4] = __float2bfloat16(a1.x); tmp[5] = __float2bfloat16(a1.y);
    tmp[6] = __float2bfloat16(a1.z); tmp[7] = __float2bfloat16(a1.w);
    *(bh8*)&Pm[idx] = *(bh8*)tmp;
}

// ======================= fill cls rows =======================
__global__ __launch_bounds__(384) void fill_cls_kernel(
    const float* __restrict__ cls, const float* __restrict__ pos, float* __restrict__ h)
{
    h[(size_t)blockIdx.x * SS * HH + threadIdx.x] = cls[threadIdx.x] + pos[threadIdx.x];
}

// ======================= LayerNorm (fp32 in -> bf16 out) =======================
__global__ __launch_bounds__(256) void ln_kernel(
    const float* __restrict__ x, const float* __restrict__ w,
    const float* __restrict__ b, bf16* __restrict__ out, int nrows)
{
    int wave = threadIdx.x >> 6;
    int lane = threadIdx.x & 63;
    int row = blockIdx.x * 4 + wave;
    if (row >= nrows) return;
    const float* xr = x + (size_t)row * HH;
    float vals[6];
    float s = 0.f;
    #pragma unroll
    for (int i = 0; i < 6; ++i) { vals[i] = xr[lane + 64 * i]; s += vals[i]; }
    #pragma unroll
    for (int mask = 32; mask >= 1; mask >>= 1) s += __shfl_xor(s, mask);
    float mean = s * (1.f / HH);
    float vs = 0.f;
    #pragma unroll
    for (int i = 0; i < 6; ++i) { float d = vals[i] - mean; vs += d * d; }
    #pragma unroll
    for (int mask = 32; mask >= 1; mask >>= 1) vs += __shfl_xor(vs, mask);
    float rstd = rsqrtf(vs * (1.f / HH) + 1e-5f);
    bf16* outr = out + (size_t)row * HH;
    #pragma unroll
    for (int i = 0; i < 6; ++i) {
        int jj = lane + 64 * i;
        outr[jj] = __float2bfloat16((vals[i] - mean) * rstd * w[jj] + b[jj]);
    }
}

// ======================= V transpose per layer: qkv v-section -> vt[bh][d][s] =======================
// grid (33, 2, 96), block 256 (32x8)
__global__ __launch_bounds__(256) void vt_kernel(
    const bf16* __restrict__ qkv, bf16* __restrict__ vt)
{
    __shared__ bf16 tile[32][33];
    int bh = blockIdx.z;
    int b = bh / NHEAD, hd = bh % NHEAD;
    int s0 = blockIdx.x * 32, d0 = blockIdx.y * 32;
    int tx = threadIdx.x & 31, ty = threadIdx.x >> 5;
    const bf16* src = qkv + ((size_t)b * SS) * QS + 768 + hd * DH;
    #pragma unroll
    for (int i = 0; i < 32; i += 8) {
        int s = s0 + ty + i;
        tile[ty + i][tx] = (s < SS) ? src[(size_t)s * QS + d0 + tx]
                                    : __float2bfloat16(0.f);
    }
    __syncthreads();
    #pragma unroll
    for (int i = 0; i < 32; i += 8)
        vt[((size_t)bh * DH + d0 + ty + i) * SSP + s0 + tx] = tile[tx][ty + i];
}

// ======================= MFMA GEMM v2 (m97-style) =======================
// A[M][K]bf16 x Bt[N][K]bf16; 128x128 tile, GBK=64, global_load_lds + XOR swizzle.
// MODE 0: out bf16 = acc + bias
// MODE 1: out bf16 = gelu(acc + bias)
// MODE 2: out f32  = acc + bias + res[row*N+col]
// MODE 3: patch embed scatter: h[b*SS+1+p][col] = acc + bias + pos[(1+p)*HH+col]
template<int MODE>
__global__ __launch_bounds__(256) void gemm_v2_kernel(
    const bf16* __restrict__ A, const bf16* __restrict__ Bt,
    const float* __restrict__ bias, const float* __restrict__ res,
    void* __restrict__ out, int M, int N, int K)
{
    __shared__ bf16 As[128 * 64];
    __shared__ bf16 Bs[128 * 64];

    int t = threadIdx.x;
    int w = t >> 6, lane = t & 63;
    int quad = lane >> 4, l15 = lane & 15;
    int bm = blockIdx.x * 128, bn = blockIdx.y * 128;
    int wm = (w >> 1) * 64, wn = (w & 1) * 64;

    int srow = lane >> 3;
    int scol = lane & 7;

    f4x acc[4][4];
    #pragma unroll
    for (int i = 0; i < 4; ++i)
        #pragma unroll
        for (int j = 0; j < 4; ++j) acc[i][j] = 0.f;

    for (int k0 = 0; k0 < K; k0 += 64) {
        #pragma unroll
        for (int p = 0; p < 4; ++p) {
            int c = w * 4 + p;
            int r = c * 8 + srow;
            int gcb = scol ^ (r & 7);
            gload16(A + (size_t)(bm + r) * K + k0 + gcb * 8, &As[c * 8 * 64]);
        }
        #pragma unroll
        for (int p = 0; p < 4; ++p) {
            int c = w * 4 + p;
            int r = c * 8 + srow;
            int gcb = scol ^ (r & 7);
            gload16(Bt + (size_t)(bn + r) * K + k0 + gcb * 8, &Bs[c * 8 * 64]);
        }
        __syncthreads();

        #pragma unroll
        for (int kc = 0; kc < 2; ++kc) {
            bh8 bfr[4];
            #pragma unroll
            for (int nf = 0; nf < 4; ++nf) {
                int rn = wn + nf * 16 + l15;
                int pcb = (kc * 4 + quad) ^ (rn & 7);
                bfr[nf] = *(const bh8*)&Bs[rn * 64 + pcb * 8];
            }
            #pragma unroll
            for (int mf = 0; mf < 4; ++mf) {
                int rm = wm + mf * 16 + l15;
                int pcb = (kc * 4 + quad) ^ (rm & 7);
                bh8 afr = *(const bh8*)&As[rm * 64 + pcb * 8];
                #pragma unroll
                for (int nf = 0; nf < 4; ++nf)
                    acc[mf][nf] = __builtin_amdgcn_mfma_f32_16x16x32_bf16(
                        afr, bfr[nf], acc[mf][nf], 0, 0, 0);
            }
        }
        __syncthreads();
    }

    #pragma unroll
    for (int mf = 0; mf < 4; ++mf) {
        #pragma unroll
        for (int nf = 0; nf < 4; ++nf) {
            f4x v = acc[mf][nf];
            int col = bn + wn + nf * 16 + l15;
            float bsv = bias[col];
            #pragma unroll
            for (int r = 0; r < 4; ++r) {
                int row = bm + wm + mf * 16 + quad * 4 + r;
                float val = v[r] + bsv;
                if (MODE == 0) {
                    if (row < M) ((bf16*)out)[(size_t)row * N + col] = __float2bfloat16(val);
                } else if (MODE == 1) {
                    float u = val;
                    float z = 0.7978845608028654f * (u + 0.044715f * u * u * u);
                    z = fminf(fmaxf(z, -15.f), 15.f);
                    float e = __expf(2.f * z);
                    float g = 0.5f * u * (1.f + (e - 1.f) / (e + 1.f));
                    if (row < M) ((bf16*)out)[(size_t)row * N + col] = __float2bfloat16(g);
                } else if (MODE == 2) {
                    if (row < M) {
                        float* o = (float*)out;
                        o[(size_t)row * N + col] = val + res[(size_t)row * N + col];
                    }
                } else {  // MODE 3
                    int b2 = row >> 10, p2 = row & 1023;
                    size_t orow = (size_t)b2 * SS + 1 + p2;
                    ((float*)out)[orow * HH + col] = val + res[(size_t)(1 + p2) * HH + col];
                }
            }
        }
    }
}

// ======================= Fused MFMA attention v3 =======================
// grid (96, 17): bh fastest for L2 K/V reuse. block 256 (4 waves, 16 q-rows each).
// Q/K staged from fused qkv; V staged from pre-transposed vt[bh][d][s].
__global__ __launch_bounds__(256) void attn_v3_kernel(
    const bf16* __restrict__ qkv, const bf16* __restrict__ vt,
    bf16* __restrict__ o)
{
    __shared__ bf16 Qs[64 * 64];
    __shared__ bf16 Ks[64 * 64];
    __shared__ bf16 Vs[64 * 64];
    __shared__ bf16 Ps[64 * 72];

    int t = threadIdx.x, w = t >> 6, lane = t & 63;
    int quad = lane >> 4, l15 = lane & 15;
    int bh = blockIdx.x;
    int b = bh / NHEAD, hd = bh % NHEAD;
    int q0 = blockIdx.y * 64;
    size_t qbase = ((size_t)b * SS) * QS + hd * DH;
    size_t kbase = qbase + 384;
    size_t vbase = (size_t)bh * DH * SSP;
    size_t obase = ((size_t)b * SS) * HH + hd * DH;

    int srow = lane >> 3, scol = lane & 7;
    int gcb = scol ^ srow;   // chunk rows satisfy r&7 == srow

    // stage Q tile (over-reads past S are discarded at output; data is finite)
    #pragma unroll
    for (int p = 0; p < 2; ++p) {
        int c = w * 2 + p;
        int r = c * 8 + srow;
        gload16(qkv + qbase + (size_t)(q0 + r) * QS + gcb * 8, &Qs[c * 512]);
    }
    __syncthreads();

    bh8 qfrag[2];
    {
        int rm = 16 * w + l15;
        #pragma unroll
        for (int kc = 0; kc < 2; ++kc)
            qfrag[kc] = *(const bh8*)&Qs[rm * 64 + ((kc * 4 + quad) ^ (rm & 7)) * 8];
    }

    f4x oacc[4];
    #pragma unroll
    for (int i = 0; i < 4; ++i) oacc[i] = 0.f;
    float m_run[4], l_run[4];
    #pragma unroll
    for (int r = 0; r < 4; ++r) { m_run[r] = -1e30f; l_run[r] = 0.f; }

    for (int c0 = 0; c0 < SS; c0 += 64) {
        __syncthreads();
        // stage K (seq-major) and V^T (d-major) tiles
        #pragma unroll
        for (int p = 0; p < 2; ++p) {
            int c = w * 2 + p;
            int r = c * 8 + srow;
            gload16(qkv + kbase + (size_t)(c0 + r) * QS + gcb * 8, &Ks[c * 512]);
            gload16(vt + vbase + (size_t)r * SSP + c0 + gcb * 8, &Vs[c * 512]);
        }
        __syncthreads();

        // S = (Q K^T) * scale
        f4x s[4];
        #pragma unroll
        for (int nf = 0; nf < 4; ++nf) {
            s[nf] = 0.f;
            int rn = nf * 16 + l15;
            #pragma unroll
            for (int kc = 0; kc < 2; ++kc) {
                bh8 kf = *(const bh8*)&Ks[rn * 64 + ((kc * 4 + quad) ^ (rn & 7)) * 8];
                s[nf] = __builtin_amdgcn_mfma_f32_16x16x32_bf16(qfrag[kc], kf, s[nf], 0, 0, 0);
            }
            bool ok = (c0 + rn) < SS;
            #pragma unroll
            for (int r = 0; r < 4; ++r)
                s[nf][r] = ok ? s[nf][r] * 0.125f : -1e30f;
        }

        // online softmax
        float mnew[4];
        #pragma unroll
        for (int r = 0; r < 4; ++r) {
            float m0 = fmaxf(fmaxf(s[0][r], s[1][r]), fmaxf(s[2][r], s[3][r]));
            #pragma unroll
            for (int mask = 8; mask >= 1; mask >>= 1)
                m0 = fmaxf(m0, __shfl_xor(m0, mask));
            mnew[r] = m0;
        }
        float al[4];
        #pragma unroll
        for (int r = 0; r < 4; ++r) {
            float mn = fmaxf(m_run[r], mnew[r]);
            al[r] = __expf(m_run[r] - mn);
            m_run[r] = mn;
        }
        float rs[4] = {0.f, 0.f, 0.f, 0.f};
        #pragma unroll
        for (int nf = 0; nf < 4; ++nf)
            #pragma unroll
            for (int r = 0; r < 4; ++r) {
                float p = __expf(s[nf][r] - m_run[r]);
                s[nf][r] = p;
                rs[r] += p;
            }
        #pragma unroll
        for (int r = 0; r < 4; ++r) {
            float t0 = rs[r];
            #pragma unroll
            for (int mask = 8; mask >= 1; mask >>= 1)
                t0 += __shfl_xor(t0, mask);
            l_run[r] = l_run[r] * al[r] + t0;
        }
        #pragma unroll
        for (int nf2 = 0; nf2 < 4; ++nf2)
            #pragma unroll
            for (int r = 0; r < 4; ++r)
                oacc[nf2][r] *= al[r];

        // P C-layout -> A-layout via wave-private LDS band (no barrier needed)
        #pragma unroll
        for (int nf = 0; nf < 4; ++nf)
            #pragma unroll
            for (int r = 0; r < 4; ++r)
                Ps[(16 * w + quad * 4 + r) * 72 + nf * 16 + l15] = __float2bfloat16(s[nf][r]);

        bh8 pf[2];
        #pragma unroll
        for (int kc = 0; kc < 2; ++kc)
            pf[kc] = *(const bh8*)&Ps[(16 * w + l15) * 72 + kc * 32 + quad * 8];

        // O += P V
        #pragma unroll
        for (int nf2 = 0; nf2 < 4; ++nf2) {
            int rn = nf2 * 16 + l15;
            #pragma unroll
            for (int kc = 0; kc < 2; ++kc) {
                bh8 vf = *(const bh8*)&Vs[rn * 64 + ((kc * 4 + quad) ^ (rn & 7)) * 8];
                oacc[nf2] = __builtin_amdgcn_mfma_f32_16x16x32_bf16(pf[kc], vf, oacc[nf2], 0, 0, 0);
            }
        }
    }

    #pragma unroll
    for (int nf2 = 0; nf2 < 4; ++nf2)
        #pragma unroll
        for (int r = 0; r < 4; ++r) {
            int row = q0 + 16 * w + quad * 4 + r;
            if (row < SS)
                o[obase + (size_t)row * HH + nf2 * 16 + l15] =
                    __float2bfloat16(oacc[nf2][r] / l_run[r]);
        }
}

// ======================= Classifier v2: grid (16 n-chunks, B) =======================
__global__ __launch_bounds__(256) void cls_kernel(
    const float* __restrict__ h, const float* __restrict__ wc,
    const float* __restrict__ bc, float* __restrict__ out)
{
    __shared__ float hr[HH];
    __shared__ float part[4][64];
    int b = blockIdx.y, n0 = blockIdx.x * 64;
    int t = threadIdx.x;
    for (int i = t; i < HH; i += 256) hr[i] = h[(size_t)b * SS * HH + i];
    __syncthreads();
    int nn = t & 63, seg = t >> 6;
    int n = n0 + nn;
    float acc = 0.f;
    if (n < NC) {
        #pragma unroll 4
        for (int kk = seg * 96; kk < seg * 96 + 96; ++kk)
            acc += hr[kk] * wc[(size_t)kk * NC + n];
    }
    part[seg][nn] = acc;
    __syncthreads();
    if (t < 64 && n0 + t < NC)
        out[b * NC + n0 + t] = part[0][t] + part[1][t] + part[2][t] + part[3][t] + bc[n0 + t];
}

// ======================= Launch =======================
extern "C" void kernel_launch(void* const* d_in, const int* in_sizes, int n_in,
                              void* d_out, int out_size, void* d_ws, size_t ws_size,
                              hipStream_t stream) {
    const float* x        = (const float*)d_in[0];
    const float* conv_w   = (const float*)d_in[1];
    const float* conv_b   = (const float*)d_in[2];
    const float* cls_tok  = (const float*)d_in[3];
    const float* pos_emb  = (const float*)d_in[4];
    const float* ln1_w    = (const float*)d_in[5];
    const float* ln1_b    = (const float*)d_in[6];
    const float* wq       = (const float*)d_in[7];
    const float* bq       = (const float*)d_in[8];
    const float* wk       = (const float*)d_in[9];
    const float* bk       = (const float*)d_in[10];
    const float* wv       = (const float*)d_in[11];
    const float* bv       = (const float*)d_in[12];
    const float* wo       = (const float*)d_in[13];
    const float* bo       = (const float*)d_in[14];
    const float* ln2_w    = (const float*)d_in[15];
    const float* ln2_b    = (const float*)d_in[16];
    const float* w1       = (const float*)d_in[17];
    const float* b1       = (const float*)d_in[18];
    const float* w2       = (const float*)d_in[19];
    const float* b2       = (const float*)d_in[20];
    const float* wc       = (const float*)d_in[21];
    const float* bc       = (const float*)d_in[22];
    float* out = (float*)d_out;

    char* wp = (char*)d_ws;
    float* h   = (float*)wp;  wp += (size_t)MROWS * HH * 4;          // 25.2 MB
    // hn (12.68 MB) and vtb (13.37 MB) share one region: hn is dead from
    // the moment the QKV GEMM has consumed it until ln2 rewrites it, and
    // vtb is only alive between vt_kernel and attn (stream-ordered).
    bf16* hn   = (bf16*)wp;
    bf16* vtb  = (bf16*)wp;   wp += (size_t)96 * DH * SSP * 2;       // 13.4 MB
    bf16* tb   = (bf16*)wp;   wp += (size_t)MPAD * HH * 2;           // 12.7 MB
    bf16* mb   = (bf16*)wp;   wp += (size_t)MPAD * II * 2;           // 50.7 MB
    bf16* qkvb = mb;          // qkv [MROWS][1152] aliases mb (disjoint lifetimes)
    bf16* Pm   = mb;          // patch matrix aliases mb too
    bf16* wqkv = (bf16*)wp;   wp += (size_t)LL * QS * HH * 2;        // 10.6 MB
    bf16* wot  = (bf16*)wp;   wp += (size_t)LL * HH * HH * 2;        // 3.5 MB
    bf16* w1t  = (bf16*)wp;   wp += (size_t)LL * HH * II * 2;        // 14.2 MB
    bf16* w2t  = (bf16*)wp;   wp += (size_t)LL * II * HH * 2;        // 14.2 MB
    bf16* cwb  = (bf16*)wp;   wp += (size_t)HH * KPATCH * 2;         // 0.6 MB
    float* cbias = (float*)wp; wp += (size_t)LL * QS * 4;            // 55 KB

    // ---- weight prep ----
    transpose_cast_kernel<<<dim3(12, 12, LL), 256, 0, stream>>>(wq, wqkv,          HH, HH, QS * HH);
    transpose_cast_kernel<<<dim3(12, 12, LL), 256, 0, stream>>>(wk, wqkv + 147456, HH, HH, QS * HH);
    transpose_cast_kernel<<<dim3(12, 12, LL), 256, 0, stream>>>(wv, wqkv + 294912, HH, HH, QS * HH);
    transpose_cast_kernel<<<dim3(12, 12, LL), 256, 0, stream>>>(wo, wot, HH, HH, HH * HH);
    transpose_cast_kernel<<<dim3(48, 12, LL), 256, 0, stream>>>(w1, w1t, HH, II, HH * II);
    transpose_cast_kernel<<<dim3(12, 48, LL), 256, 0, stream>>>(w2, w2t, II, HH, II * HH);
    cast_kernel<<<288, 256, 0, stream>>>(conv_w, cwb, HH * KPATCH);
    bias_concat_kernel<<<LL, 384, 0, stream>>>(bq, bk, bv, cbias);

    // ---- patch embed as GEMM ----
    im2row_kernel<<<6144, 256, 0, stream>>>(x, Pm);
    gemm_v2_kernel<3><<<dim3(128, 3), 256, 0, stream>>>(
        Pm, cwb, conv_b, pos_emb, h, MPATCH, HH, KPATCH);
    fill_cls_kernel<<<BB, 384, 0, stream>>>(cls_tok, pos_emb, h);

    const int M = MROWS;
    dim3 gQKV(129, 9);   // N=1152
    dim3 gH(129, 3);     // N=384
    dim3 gI(129, 12);    // N=1536

    for (int l = 0; l < LL; ++l) {
        const float* l1w = ln1_w + (size_t)l * HH;
        const float* l1b = ln1_b + (size_t)l * HH;
        const float* l2w = ln2_w + (size_t)l * HH;
        const float* l2b = ln2_b + (size_t)l * HH;
        const bf16* wqkv_l = wqkv + (size_t)l * QS * HH;
        const bf16* wo_l   = wot  + (size_t)l * HH * HH;
        const bf16* w1_l   = w1t  + (size_t)l * HH * II;
        const bf16* w2_l   = w2t  + (size_t)l * II * HH;
        const float* cb_l  = cbias + (size_t)l * QS;
        const float* bo_l  = bo + (size_t)l * HH;
        const float* b1_l  = b1 + (size_t)l * II;
        const float* b2_l  = b2 + (size_t)l * HH;

        ln_kernel<<<4100, 256, 0, stream>>>(h, l1w, l1b, hn, M);

        gemm_v2_kernel<0><<<gQKV, 256, 0, stream>>>(hn, wqkv_l, cb_l, nullptr, qkvb, M, QS, HH);

        vt_kernel<<<dim3(33, 2, 96), 256, 0, stream>>>(qkvb, vtb);

        attn_v3_kernel<<<dim3(96, 17), 256, 0, stream>>>(qkvb, vtb, tb);

        gemm_v2_kernel<2><<<gH, 256, 0, stream>>>(tb, wo_l, bo_l, h, h, M, HH, HH);

        ln_kernel<<<4100, 256, 0, stream>>>(h, l2w, l2b, hn, M);

        gemm_v2_kernel<1><<<gI, 256, 0, stream>>>(hn, w1_l, b1_l, nullptr, mb, M, II, HH);
        gemm_v2_kernel<2><<<gH, 256, 0, stream>>>(mb, w2_l, b2_l, h, h, M, HH, II);
    }

    cls_kernel<<<dim3(16, BB), 256, 0, stream>>>(h, wc, bc, out);
}

// Round 5
// 3263.961 us; speedup vs baseline: 19.1366x; 1.2156x over previous
//
#include <hip/hip_runtime.h>
#include <hip/hip_bf16.h>
#include <math.h>

// ---- Model constants ----
#define BB 16
#define HH 384
#define NHEAD 6
#define DH 64
#define LL 12
#define II 1536
#define NC 1000
#define SS 1025
#define MROWS (BB * SS)      // 16400
#define MPAD  16512          // MROWS padded to multiple of 128
#define KPATCH 768           // 3*16*16
#define MPATCH (BB * 1024)   // 16384
#define QS 1152              // fused qkv row stride
#define SSP 1088             // padded seq stride for V^T (17*64)

typedef __hip_bfloat16 bf16;
typedef __attribute__((ext_vector_type(8))) short bh8;   // 8 bf16 (MFMA A/B frag)
typedef __attribute__((ext_vector_type(4))) float f4x;   // MFMA C/D frag

__device__ __forceinline__ void gload16(const bf16* g, bf16* l) {
    __builtin_amdgcn_global_load_lds(
        (const __attribute__((address_space(1))) unsigned int*)g,
        (__attribute__((address_space(3))) unsigned int*)l, 16, 0, 0);
}

__device__ __forceinline__ unsigned short bf16_bits(float f) {
    __hip_bfloat16 h = __float2bfloat16(f);
    return *reinterpret_cast<unsigned short*>(&h);
}
__device__ __forceinline__ ushort4 pack4_bf16(float a, float b, float c, float d) {
    ushort4 u;
    u.x = bf16_bits(a); u.y = bf16_bits(b); u.z = bf16_bits(c); u.w = bf16_bits(d);
    return u;
}

// ======================= transpose + cast: [L][K][N] f32 -> [L][N][K] bf16 =======================
__global__ __launch_bounds__(256) void transpose_cast_kernel(
    const float* __restrict__ in, bf16* __restrict__ out, int K, int N, int ostride)
{
    __shared__ float tile[32][33];
    int l = blockIdx.z;
    const float* ip = in + (size_t)l * K * N;
    bf16* op = out + (size_t)l * ostride;
    int n0 = blockIdx.x * 32, k0 = blockIdx.y * 32;
    int tx = threadIdx.x & 31, ty = threadIdx.x >> 5;   // 32 x 8
    #pragma unroll
    for (int i = 0; i < 32; i += 8)
        tile[ty + i][tx] = ip[(size_t)(k0 + ty + i) * N + n0 + tx];
    __syncthreads();
    #pragma unroll
    for (int i = 0; i < 32; i += 8)
        op[(size_t)(n0 + ty + i) * K + k0 + tx] = __float2bfloat16(tile[tx][ty + i]);
}

// ======================= plain cast f32 -> bf16 =======================
__global__ __launch_bounds__(256) void cast_kernel(
    const float* __restrict__ in, bf16* __restrict__ out, int n)
{
    int i = blockIdx.x * 1024 + threadIdx.x * 4;
    if (i + 3 < n) {
        float4 v = *(const float4*)&in[i];
        out[i]   = __float2bfloat16(v.x);
        out[i+1] = __float2bfloat16(v.y);
        out[i+2] = __float2bfloat16(v.z);
        out[i+3] = __float2bfloat16(v.w);
    } else {
        for (int j = i; j < n; ++j) out[j] = __float2bfloat16(in[j]);
    }
}

// ======================= concat qkv biases: cb[l][1152] =======================
__global__ __launch_bounds__(384) void bias_concat_kernel(
    const float* __restrict__ bq, const float* __restrict__ bk,
    const float* __restrict__ bv, float* __restrict__ cb)
{
    int l = blockIdx.x, t = threadIdx.x;
    cb[l * QS + t]       = bq[l * HH + t];
    cb[l * QS + 384 + t] = bk[l * HH + t];
    cb[l * QS + 768 + t] = bv[l * HH + t];
}

// ======================= im2row: x[B,3,512,512] -> Pm[16384][768] bf16 =======================
__global__ __launch_bounds__(256) void im2row_kernel(
    const float* __restrict__ x, bf16* __restrict__ Pm)
{
    size_t idx = ((size_t)blockIdx.x * 256 + threadIdx.x) * 8;
    int kk = (int)(idx % KPATCH);
    int m  = (int)(idx / KPATCH);
    int b = m >> 10, p = m & 1023;
    int c = kk >> 8, rem = kk & 255, py = rem >> 4, px = rem & 15;
    int pi = p >> 5, pj = p & 31;
    const float* src = &x[(((size_t)b * 3 + c) * 512 + pi * 16 + py) * 512 + pj * 16 + px];
    float4 a0 = *(const float4*)src;
    float4 a1 = *(const float4*)(src + 4);
    bf16 tmp[8];
    tmp[0] = __float2bfloat16(a0.x); tmp[1] = __float2bfloat16(a0.y);
    tmp[2] = __float2bfloat16(a0.z); tmp[3] = __float2bfloat16(a0.w);
    tmp[4] = __float2bfloat16(a1.x); tmp[5] = __float2bfloat16(a1.y);
    tmp[6] = __float2bfloat16(a1.z); tmp[7] = __float2bfloat16(a1.w);
    *(bh8*)&Pm[idx] = *(bh8*)tmp;
}

// ======================= fill cls rows =======================
__global__ __launch_bounds__(384) void fill_cls_kernel(
    const float* __restrict__ cls, const float* __restrict__ pos, float* __restrict__ h)
{
    h[(size_t)blockIdx.x * SS * HH + threadIdx.x] = cls[threadIdx.x] + pos[threadIdx.x];
}

// ======================= LayerNorm (fp32 in -> bf16 out) =======================
__global__ __launch_bounds__(256) void ln_kernel(
    const float* __restrict__ x, const float* __restrict__ w,
    const float* __restrict__ b, bf16* __restrict__ out, int nrows)
{
    int wave = threadIdx.x >> 6;
    int lane = threadIdx.x & 63;
    int row = blockIdx.x * 4 + wave;
    if (row >= nrows) return;
    const float* xr = x + (size_t)row * HH;
    float vals[6];
    float s = 0.f;
    #pragma unroll
    for (int i = 0; i < 6; ++i) { vals[i] = xr[lane + 64 * i]; s += vals[i]; }
    #pragma unroll
    for (int mask = 32; mask >= 1; mask >>= 1) s += __shfl_xor(s, mask);
    float mean = s * (1.f / HH);
    float vs = 0.f;
    #pragma unroll
    for (int i = 0; i < 6; ++i) { float d = vals[i] - mean; vs += d * d; }
    #pragma unroll
    for (int mask = 32; mask >= 1; mask >>= 1) vs += __shfl_xor(vs, mask);
    float rstd = rsqrtf(vs * (1.f / HH) + 1e-5f);
    bf16* outr = out + (size_t)row * HH;
    #pragma unroll
    for (int i = 0; i < 6; ++i) {
        int jj = lane + 64 * i;
        outr[jj] = __float2bfloat16((vals[i] - mean) * rstd * w[jj] + b[jj]);
    }
}

// ======================= V transpose per layer: qkv v-section -> vt[bh][d][s] =======================
__global__ __launch_bounds__(256) void vt_kernel(
    const bf16* __restrict__ qkv, bf16* __restrict__ vt)
{
    __shared__ bf16 tile[32][33];
    int bh = blockIdx.z;
    int b = bh / NHEAD, hd = bh % NHEAD;
    int s0 = blockIdx.x * 32, d0 = blockIdx.y * 32;
    int tx = threadIdx.x & 31, ty = threadIdx.x >> 5;
    const bf16* src = qkv + ((size_t)b * SS) * QS + 768 + hd * DH;
    #pragma unroll
    for (int i = 0; i < 32; i += 8) {
        int s = s0 + ty + i;
        tile[ty + i][tx] = (s < SS) ? src[(size_t)s * QS + d0 + tx]
                                    : __float2bfloat16(0.f);
    }
    __syncthreads();
    #pragma unroll
    for (int i = 0; i < 32; i += 8)
        vt[((size_t)bh * DH + d0 + ty + i) * SSP + s0 + tx] = tile[tx][ty + i];
}

// ======================= MFMA GEMM v3 (C^T accum, vectorized epilogue) =======================
// A[M][K]bf16 x Bt[N][K]bf16; 128x128 tile, GBK=64, global_load_lds + XOR swizzle.
// acc = mfma(bfr, afr): lane holds out-row = l15-band (fixed), 4 contiguous cols per reg.
// MODE 0: out bf16 = acc + bias
// MODE 1: out bf16 = gelu(acc + bias)
// MODE 2: out f32  = acc + bias + res[row*N+col]
// MODE 3: patch embed scatter: h[b*SS+1+p][col] = acc + bias + pos[(1+p)*HH+col]
template<int MODE>
__global__ __launch_bounds__(256) void gemm_v2_kernel(
    const bf16* __restrict__ A, const bf16* __restrict__ Bt,
    const float* __restrict__ bias, const float* __restrict__ res,
    void* __restrict__ out, int M, int N, int K)
{
    __shared__ bf16 As[128 * 64];
    __shared__ bf16 Bs[128 * 64];

    int t = threadIdx.x;
    int w = t >> 6, lane = t & 63;
    int quad = lane >> 4, l15 = lane & 15;
    int bm = blockIdx.x * 128, bn = blockIdx.y * 128;
    int wm = (w >> 1) * 64, wn = (w & 1) * 64;

    int srow = lane >> 3;
    int scol = lane & 7;

    f4x acc[4][4];
    #pragma unroll
    for (int i = 0; i < 4; ++i)
        #pragma unroll
        for (int j = 0; j < 4; ++j) acc[i][j] = 0.f;

    for (int k0 = 0; k0 < K; k0 += 64) {
        #pragma unroll
        for (int p = 0; p < 4; ++p) {
            int c = w * 4 + p;
            int r = c * 8 + srow;
            int gcb = scol ^ (r & 7);
            gload16(A + (size_t)(bm + r) * K + k0 + gcb * 8, &As[c * 8 * 64]);
        }
        #pragma unroll
        for (int p = 0; p < 4; ++p) {
            int c = w * 4 + p;
            int r = c * 8 + srow;
            int gcb = scol ^ (r & 7);
            gload16(Bt + (size_t)(bn + r) * K + k0 + gcb * 8, &Bs[c * 8 * 64]);
        }
        __syncthreads();

        #pragma unroll
        for (int kc = 0; kc < 2; ++kc) {
            bh8 bfr[4];
            #pragma unroll
            for (int nf = 0; nf < 4; ++nf) {
                int rn = wn + nf * 16 + l15;
                int pcb = (kc * 4 + quad) ^ (rn & 7);
                bfr[nf] = *(const bh8*)&Bs[rn * 64 + pcb * 8];
            }
            #pragma unroll
            for (int mf = 0; mf < 4; ++mf) {
                int rm = wm + mf * 16 + l15;
                int pcb = (kc * 4 + quad) ^ (rm & 7);
                bh8 afr = *(const bh8*)&As[rm * 64 + pcb * 8];
                #pragma unroll
                for (int nf = 0; nf < 4; ++nf)
                    acc[mf][nf] = __builtin_amdgcn_mfma_f32_16x16x32_bf16(
                        bfr[nf], afr, acc[mf][nf], 0, 0, 0);
            }
        }
        __syncthreads();
    }

    #pragma unroll
    for (int mf = 0; mf < 4; ++mf) {
        int row = bm + wm + mf * 16 + l15;
        #pragma unroll
        for (int nf = 0; nf < 4; ++nf) {
            f4x v = acc[mf][nf];
            int col0 = bn + wn + nf * 16 + quad * 4;
            float4 b4 = *(const float4*)&bias[col0];
            float vals[4];
            #pragma unroll
            for (int r = 0; r < 4; ++r) vals[r] = v[r] + (&b4.x)[r];
            if (MODE == 0) {
                if (row < M)
                    *(ushort4*)&((bf16*)out)[(size_t)row * N + col0] =
                        pack4_bf16(vals[0], vals[1], vals[2], vals[3]);
            } else if (MODE == 1) {
                #pragma unroll
                for (int r = 0; r < 4; ++r) {
                    float u = vals[r];
                    float z = 0.7978845608028654f * (u + 0.044715f * u * u * u);
                    z = fminf(fmaxf(z, -15.f), 15.f);
                    float e = __expf(2.f * z);
                    vals[r] = 0.5f * u * (1.f + (e - 1.f) / (e + 1.f));
                }
                if (row < M)
                    *(ushort4*)&((bf16*)out)[(size_t)row * N + col0] =
                        pack4_bf16(vals[0], vals[1], vals[2], vals[3]);
            } else if (MODE == 2) {
                if (row < M) {
                    float* o = (float*)out;
                    float4 r4 = *(const float4*)&res[(size_t)row * N + col0];
                    float4 st = {vals[0] + r4.x, vals[1] + r4.y,
                                 vals[2] + r4.z, vals[3] + r4.w};
                    *(float4*)&o[(size_t)row * N + col0] = st;
                }
            } else {  // MODE 3
                int b2 = row >> 10, p2 = row & 1023;
                size_t orow = (size_t)b2 * SS + 1 + p2;
                float4 r4 = *(const float4*)&res[(size_t)(1 + p2) * HH + col0];
                float4 st = {vals[0] + r4.x, vals[1] + r4.y,
                             vals[2] + r4.z, vals[3] + r4.w};
                *(float4*)&((float*)out)[orow * HH + col0] = st;
            }
        }
    }
}

// ======================= Fused MFMA attention v4 (transposed, fixed-shift softmax) =======================
// grid (96, 17): bh fastest for L2 K/V reuse. block 256 (4 waves, 16 q-rows each).
// S^T = mfma(K, Q^T); P = exp2(S*c1 + c2) (fixed shift, cancels in normalize);
// O^T = mfma(V^T, P^T). Lane l15 = one q-row: l-sum is register-accumulated,
// reduced across quads once after the loop.
#define PSTR 68   // Ps row stride (elems): 4-aligned for b64 writes

__global__ __launch_bounds__(256) void attn_v4_kernel(
    const bf16* __restrict__ qkv, const bf16* __restrict__ vt,
    bf16* __restrict__ o)
{
    __shared__ bf16 Qs[64 * 64];
    __shared__ bf16 Ks[64 * 64];
    __shared__ bf16 Vs[64 * 64];
    __shared__ bf16 Ps[4][16 * PSTR];

    int t = threadIdx.x, w = t >> 6, lane = t & 63;
    int quad = lane >> 4, l15 = lane & 15;
    int bh = blockIdx.x;
    int b = bh / NHEAD, hd = bh % NHEAD;
    int q0 = blockIdx.y * 64;
    size_t qbase = ((size_t)b * SS) * QS + hd * DH;
    size_t kbase = qbase + 384;
    size_t vbase = (size_t)bh * DH * SSP;
    size_t obase = ((size_t)b * SS) * HH + hd * DH;

    int srow = lane >> 3, scol = lane & 7;
    int gcb = scol ^ srow;

    // stage Q tile
    #pragma unroll
    for (int p = 0; p < 2; ++p) {
        int c = w * 2 + p;
        int r = c * 8 + srow;
        gload16(qkv + qbase + (size_t)(q0 + r) * QS + gcb * 8, &Qs[c * 512]);
    }
    __syncthreads();

    bh8 qfrag[2];
    {
        int rm = 16 * w + l15;
        #pragma unroll
        for (int kc = 0; kc < 2; ++kc)
            qfrag[kc] = *(const bh8*)&Qs[rm * 64 + ((kc * 4 + quad) ^ (rm & 7)) * 8];
    }

    f4x oacc[4];
    #pragma unroll
    for (int i = 0; i < 4; ++i) oacc[i] = 0.f;
    float l_part = 0.f;

    const float C1 = 0.18033688011112042f;  // 0.125 * log2(e)
    const float C2 = -16.0f;                // fixed shift (cancels in normalize)

    for (int c0 = 0; c0 < SS; c0 += 64) {
        __syncthreads();
        #pragma unroll
        for (int p = 0; p < 2; ++p) {
            int c = w * 2 + p;
            int r = c * 8 + srow;
            gload16(qkv + kbase + (size_t)(c0 + r) * QS + gcb * 8, &Ks[c * 512]);
            gload16(vt + vbase + (size_t)r * SSP + c0 + gcb * 8, &Vs[c * 512]);
        }
        __syncthreads();

        bool tail = (c0 + 64 > SS);
        #pragma unroll
        for (int nf = 0; nf < 4; ++nf) {
            f4x s = 0.f;
            int rn = nf * 16 + l15;
            #pragma unroll
            for (int kc = 0; kc < 2; ++kc) {
                bh8 kf = *(const bh8*)&Ks[rn * 64 + ((kc * 4 + quad) ^ (rn & 7)) * 8];
                s = __builtin_amdgcn_mfma_f32_16x16x32_bf16(kf, qfrag[kc], s, 0, 0, 0);
            }
            // rows of s = keys (quad*4+r within nf-tile), col = this lane's q-row
            float pv[4];
            #pragma unroll
            for (int r = 0; r < 4; ++r) {
                float p = exp2f(fmaf(s[r], C1, C2));
                if (tail && (c0 + nf * 16 + quad * 4 + r >= SS)) p = 0.f;
                pv[r] = p;
                l_part += p;
            }
            *(ushort4*)&Ps[w][l15 * PSTR + nf * 16 + quad * 4] =
                pack4_bf16(pv[0], pv[1], pv[2], pv[3]);
        }

        // wave-private P^T read (B-frag: P[q=l15][key contig])
        bh8 pf[2];
        #pragma unroll
        for (int kc = 0; kc < 2; ++kc)
            pf[kc] = *(const bh8*)&Ps[w][l15 * PSTR + kc * 32 + quad * 8];

        // O^T += V^T * P^T
        #pragma unroll
        for (int nf2 = 0; nf2 < 4; ++nf2) {
            int rn2 = nf2 * 16 + l15;
            #pragma unroll
            for (int kc = 0; kc < 2; ++kc) {
                bh8 vf = *(const bh8*)&Vs[rn2 * 64 + ((kc * 4 + quad) ^ (rn2 & 7)) * 8];
                oacc[nf2] = __builtin_amdgcn_mfma_f32_16x16x32_bf16(vf, pf[kc], oacc[nf2], 0, 0, 0);
            }
        }
    }

    // reduce l across the 4 quads sharing this q-column
    l_part += __shfl_xor(l_part, 16);
    l_part += __shfl_xor(l_part, 32);
    float inv = 1.f / l_part;

    int row = q0 + 16 * w + l15;
    if (row < SS) {
        #pragma unroll
        for (int nf2 = 0; nf2 < 4; ++nf2) {
            // lane holds d = nf2*16 + quad*4 + r for its single q-row
            *(ushort4*)&o[obase + (size_t)row * HH + nf2 * 16 + quad * 4] =
                pack4_bf16(oacc[nf2][0] * inv, oacc[nf2][1] * inv,
                           oacc[nf2][2] * inv, oacc[nf2][3] * inv);
        }
    }
}

// ======================= Classifier: grid (16 n-chunks, B) =======================
__global__ __launch_bounds__(256) void cls_kernel(
    const float* __restrict__ h, const float* __restrict__ wc,
    const float* __restrict__ bc, float* __restrict__ out)
{
    __shared__ float hr[HH];
    __shared__ float part[4][64];
    int b = blockIdx.y, n0 = blockIdx.x * 64;
    int t = threadIdx.x;
    for (int i = t; i < HH; i += 256) hr[i] = h[(size_t)b * SS * HH + i];
    __syncthreads();
    int nn = t & 63, seg = t >> 6;
    int n = n0 + nn;
    float acc = 0.f;
    if (n < NC) {
        #pragma unroll 4
        for (int kk = seg * 96; kk < seg * 96 + 96; ++kk)
            acc += hr[kk] * wc[(size_t)kk * NC + n];
    }
    part[seg][nn] = acc;
    __syncthreads();
    if (t < 64 && n0 + t < NC)
        out[b * NC + n0 + t] = part[0][t] + part[1][t] + part[2][t] + part[3][t] + bc[n0 + t];
}

// ======================= Launch =======================
extern "C" void kernel_launch(void* const* d_in, const int* in_sizes, int n_in,
                              void* d_out, int out_size, void* d_ws, size_t ws_size,
                              hipStream_t stream) {
    const float* x        = (const float*)d_in[0];
    const float* conv_w   = (const float*)d_in[1];
    const float* conv_b   = (const float*)d_in[2];
    const float* cls_tok  = (const float*)d_in[3];
    const float* pos_emb  = (const float*)d_in[4];
    const float* ln1_w    = (const float*)d_in[5];
    const float* ln1_b    = (const float*)d_in[6];
    const float* wq       = (const float*)d_in[7];
    const float* bq       = (const float*)d_in[8];
    const float* wk       = (const float*)d_in[9];
    const float* bk       = (const float*)d_in[10];
    const float* wv       = (const float*)d_in[11];
    const float* bv       = (const float*)d_in[12];
    const float* wo       = (const float*)d_in[13];
    const float* bo       = (const float*)d_in[14];
    const float* ln2_w    = (const float*)d_in[15];
    const float* ln2_b    = (const float*)d_in[16];
    const float* w1       = (const float*)d_in[17];
    const float* b1       = (const float*)d_in[18];
    const float* w2       = (const float*)d_in[19];
    const float* b2       = (const float*)d_in[20];
    const float* wc       = (const float*)d_in[21];
    const float* bc       = (const float*)d_in[22];
    float* out = (float*)d_out;

    char* wp = (char*)d_ws;
    float* h   = (float*)wp;  wp += (size_t)MROWS * HH * 4;          // 25.2 MB
    // hn and vtb share one region (disjoint lifetimes, stream-ordered)
    bf16* hn   = (bf16*)wp;
    bf16* vtb  = (bf16*)wp;   wp += (size_t)96 * DH * SSP * 2;       // 13.4 MB
    bf16* tb   = (bf16*)wp;   wp += (size_t)MPAD * HH * 2;           // 12.7 MB
    bf16* mb   = (bf16*)wp;   wp += (size_t)MPAD * II * 2;           // 50.7 MB
    bf16* qkvb = mb;          // qkv [MROWS][1152] aliases mb
    bf16* Pm   = mb;          // patch matrix aliases mb too
    bf16* wqkv = (bf16*)wp;   wp += (size_t)LL * QS * HH * 2;        // 10.6 MB
    bf16* wot  = (bf16*)wp;   wp += (size_t)LL * HH * HH * 2;        // 3.5 MB
    bf16* w1t  = (bf16*)wp;   wp += (size_t)LL * HH * II * 2;        // 14.2 MB
    bf16* w2t  = (bf16*)wp;   wp += (size_t)LL * II * HH * 2;        // 14.2 MB
    bf16* cwb  = (bf16*)wp;   wp += (size_t)HH * KPATCH * 2;         // 0.6 MB
    float* cbias = (float*)wp; wp += (size_t)LL * QS * 4;            // 55 KB

    // ---- weight prep ----
    transpose_cast_kernel<<<dim3(12, 12, LL), 256, 0, stream>>>(wq, wqkv,          HH, HH, QS * HH);
    transpose_cast_kernel<<<dim3(12, 12, LL), 256, 0, stream>>>(wk, wqkv + 147456, HH, HH, QS * HH);
    transpose_cast_kernel<<<dim3(12, 12, LL), 256, 0, stream>>>(wv, wqkv + 294912, HH, HH, QS * HH);
    transpose_cast_kernel<<<dim3(12, 12, LL), 256, 0, stream>>>(wo, wot, HH, HH, HH * HH);
    transpose_cast_kernel<<<dim3(48, 12, LL), 256, 0, stream>>>(w1, w1t, HH, II, HH * II);
    transpose_cast_kernel<<<dim3(12, 48, LL), 256, 0, stream>>>(w2, w2t, II, HH, II * HH);
    cast_kernel<<<288, 256, 0, stream>>>(conv_w, cwb, HH * KPATCH);
    bias_concat_kernel<<<LL, 384, 0, stream>>>(bq, bk, bv, cbias);

    // ---- patch embed as GEMM ----
    im2row_kernel<<<6144, 256, 0, stream>>>(x, Pm);
    gemm_v2_kernel<3><<<dim3(128, 3), 256, 0, stream>>>(
        Pm, cwb, conv_b, pos_emb, h, MPATCH, HH, KPATCH);
    fill_cls_kernel<<<BB, 384, 0, stream>>>(cls_tok, pos_emb, h);

    const int M = MROWS;
    dim3 gQKV(129, 9);   // N=1152
    dim3 gH(129, 3);     // N=384
    dim3 gI(129, 12);    // N=1536

    for (int l = 0; l < LL; ++l) {
        const float* l1w = ln1_w + (size_t)l * HH;
        const float* l1b = ln1_b + (size_t)l * HH;
        const float* l2w = ln2_w + (size_t)l * HH;
        const float* l2b = ln2_b + (size_t)l * HH;
        const bf16* wqkv_l = wqkv + (size_t)l * QS * HH;
        const bf16* wo_l   = wot  + (size_t)l * HH * HH;
        const bf16* w1_l   = w1t  + (size_t)l * HH * II;
        const bf16* w2_l   = w2t  + (size_t)l * II * HH;
        const float* cb_l  = cbias + (size_t)l * QS;
        const float* bo_l  = bo + (size_t)l * HH;
        const float* b1_l  = b1 + (size_t)l * II;
        const float* b2_l  = b2 + (size_t)l * HH;

        ln_kernel<<<4100, 256, 0, stream>>>(h, l1w, l1b, hn, M);

        gemm_v2_kernel<0><<<gQKV, 256, 0, stream>>>(hn, wqkv_l, cb_l, nullptr, qkvb, M, QS, HH);

        vt_kernel<<<dim3(33, 2, 96), 256, 0, stream>>>(qkvb, vtb);

        attn_v4_kernel<<<dim3(96, 17), 256, 0, stream>>>(qkvb, vtb, tb);

        gemm_v2_kernel<2><<<gH, 256, 0, stream>>>(tb, wo_l, bo_l, h, h, M, HH, HH);

        ln_kernel<<<4100, 256, 0, stream>>>(h, l2w, l2b, hn, M);

        gemm_v2_kernel<1><<<gI, 256, 0, stream>>>(hn, w1_l, b1_l, nullptr, mb, M, II, HH);
        gemm_v2_kernel<2><<<gH, 256, 0, stream>>>(mb, w2_l, b2_l, h, h, M, HH, II);
    }

    cls_kernel<<<dim3(16, BB), 256, 0, stream>>>(h, wc, bc, out);
}